// Round 2
// baseline (9708.895 us; speedup 1.0000x reference)
//
#include <hip/hip_runtime.h>
#include <math.h>

#define Dk 1024
#define Hk 256
#define Lk 8192
#define Bk 8
#define MTOT (Bk*Lk)   // 65536 rows

typedef float f32x2 __attribute__((ext_vector_type(2)));

// ---------------- prep: S[j] = sum_d gamma[d]*W1[d][j], Tb[j] = sum_d beta[d]*W1[d][j] + b1[j]
__global__ __launch_bounds__(256) void prep_kernel(
    const float* __restrict__ gamma, const float* __restrict__ beta,
    const float* __restrict__ W1, const float* __restrict__ b1,
    float* __restrict__ S, float* __restrict__ Tb) {
  int j = threadIdx.x;  // 0..255
  float s = 0.f, t = 0.f;
  for (int d = 0; d < Dk; ++d) {
    float w = W1[d * Hk + j];
    s = fmaf(gamma[d], w, s);
    t = fmaf(beta[d], w, t);
  }
  S[j] = s;
  Tb[j] = t + b1[j];
}

// ---------------- scores: fused LN + Linear(1024->256) + GELU + Linear(256->1)
// Packed-fp32 (v_pk_fma_f32) microtile, LDS double-buffered (1 barrier/tile).
// FP accumulation order identical to the round-1 kernel => bit-identical scores.
__global__ __launch_bounds__(512, 4) void scores_kernel(
    const float* __restrict__ F, const float* __restrict__ gamma,
    const float* __restrict__ W1,
    const float* __restrict__ S, const float* __restrict__ Tb,
    const float* __restrict__ W2, const float* __restrict__ b2,
    float* __restrict__ scores_out) {
  __shared__ float As[2][16][132];   // k-major, +4 pad
  __shared__ float Bs[2][16][256];
  __shared__ float smu[128];
  __shared__ float srs[128];

  const int tid = threadIdx.x;
  const int tx = tid & 31;        // n dimension (32 lanes)
  const int ty = tid >> 5;        // m dimension (16)
  const int RM = blockIdx.x * 128;

  // staging indices
  const int ar  = tid >> 2;        // A row 0..127
  const int akq = (tid & 3) * 4;   // A k sub-offset {0,4,8,12}
  const int bk  = tid >> 5;        // B k row 0..15
  const int bn  = (tid & 31) * 8;  // B n offset

  const float* Aptr = F + (size_t)(RM + ar) * Dk + akq;

  float4 av, bv0, bv1, gv;
  av  = *reinterpret_cast<const float4*>(Aptr);
  bv0 = *reinterpret_cast<const float4*>(W1 + (size_t)bk * Hk + bn);
  bv1 = *reinterpret_cast<const float4*>(W1 + (size_t)bk * Hk + bn + 4);
  gv  = *reinterpret_cast<const float4*>(gamma + akq);

  f32x2 acc2[8][4];
  #pragma unroll
  for (int i = 0; i < 8; ++i)
    #pragma unroll
    for (int j = 0; j < 4; ++j) acc2[i][j] = (f32x2){0.f, 0.f};

  float rsum = 0.f, rsq = 0.f;

  // ---- stage tile 0 into buffer 0 (stats for tile 0, same fp order as before)
  rsum += av.x + av.y + av.z + av.w;
  rsq = fmaf(av.x, av.x, fmaf(av.y, av.y, fmaf(av.z, av.z, fmaf(av.w, av.w, rsq))));
  As[0][akq + 0][ar] = av.x * gv.x;
  As[0][akq + 1][ar] = av.y * gv.y;
  As[0][akq + 2][ar] = av.z * gv.z;
  As[0][akq + 3][ar] = av.w * gv.w;
  *reinterpret_cast<float4*>(&Bs[0][bk][bn])     = bv0;
  *reinterpret_cast<float4*>(&Bs[0][bk][bn + 4]) = bv1;

  for (int s = 0; s < Dk / 16; ++s) {
    __syncthreads();  // tile s visible; everyone done reading buffer s^1
    const int cur = s & 1;
    float (*Ac)[132] = As[cur];
    float (*Bc)[256] = Bs[cur];
    if (s + 1 < Dk / 16) {  // prefetch tile s+1 into regs (hides under compute)
      av  = *reinterpret_cast<const float4*>(Aptr + (s + 1) * 16);
      bv0 = *reinterpret_cast<const float4*>(W1 + (size_t)((s + 1) * 16 + bk) * Hk + bn);
      bv1 = *reinterpret_cast<const float4*>(W1 + (size_t)((s + 1) * 16 + bk) * Hk + bn + 4);
      gv  = *reinterpret_cast<const float4*>(gamma + (s + 1) * 16 + akq);
    }
    #pragma unroll
    for (int kk = 0; kk < 16; ++kk) {
      const float4 a0 = *reinterpret_cast<const float4*>(&Ac[kk][ty * 4]);
      const float4 a1 = *reinterpret_cast<const float4*>(&Ac[kk][ty * 4 + 64]);
      const float4 b0 = *reinterpret_cast<const float4*>(&Bc[kk][tx * 4]);
      const float4 b1 = *reinterpret_cast<const float4*>(&Bc[kk][tx * 4 + 128]);
      const f32x2 bb[4] = {{b0.x, b0.y}, {b0.z, b0.w}, {b1.x, b1.y}, {b1.z, b1.w}};
      const float aa[8] = {a0.x, a0.y, a0.z, a0.w, a1.x, a1.y, a1.z, a1.w};
      #pragma unroll
      for (int i = 0; i < 8; ++i) {
        const f32x2 ai = {aa[i], aa[i]};
        #pragma unroll
        for (int jp = 0; jp < 4; ++jp)
          acc2[i][jp] = __builtin_elementwise_fma(ai, bb[jp], acc2[i][jp]);
      }
    }
    if (s + 1 < Dk / 16) {  // stats (tile order 0..63 preserved) + stage into buffer s+1
      rsum += av.x + av.y + av.z + av.w;
      rsq = fmaf(av.x, av.x, fmaf(av.y, av.y, fmaf(av.z, av.z, fmaf(av.w, av.w, rsq))));
      const int nxt = cur ^ 1;
      As[nxt][akq + 0][ar] = av.x * gv.x;
      As[nxt][akq + 1][ar] = av.y * gv.y;
      As[nxt][akq + 2][ar] = av.z * gv.z;
      As[nxt][akq + 3][ar] = av.w * gv.w;
      *reinterpret_cast<float4*>(&Bs[nxt][bk][bn])     = bv0;
      *reinterpret_cast<float4*>(&Bs[nxt][bk][bn + 4]) = bv1;
    }
  }

  // finish row stats: threads 4r..4r+3 each hold a quarter of row r
  rsum += __shfl_xor(rsum, 1); rsum += __shfl_xor(rsum, 2);
  rsq  += __shfl_xor(rsq, 1);  rsq  += __shfl_xor(rsq, 2);
  if ((tid & 3) == 0) {
    float mu  = rsum * (1.f / 1024.f);
    float var = rsq * (1.f / 1024.f) - mu * mu;
    smu[ar] = mu;
    srs[ar] = rsqrtf(var + 1e-5f);
  }
  __syncthreads();

  // epilogue: LN affine + GELU(exact) + dot with W2, half-wave reduce over n
  float sj[8], tbj[8], w2j[8];
  #pragma unroll
  for (int j = 0; j < 8; ++j) {
    int nj = tx * 4 + (j < 4 ? j : 124 + j);
    sj[j] = S[nj]; tbj[j] = Tb[nj]; w2j[j] = W2[nj];
  }
  const float bias2 = b2[0];
  #pragma unroll
  for (int i = 0; i < 8; ++i) {
    int mi = ty * 4 + (i < 4 ? i : 60 + i);
    float mu = smu[mi], rs = srs[mi];
    float part = 0.f;
    #pragma unroll
    for (int j = 0; j < 8; ++j) {
      float hpre = rs * acc2[i][j >> 1][j & 1] - rs * mu * sj[j] + tbj[j];
      float h = 0.5f * hpre * (1.f + erff(hpre * 0.70710678118654752f));
      part = fmaf(h, w2j[j], part);
    }
    #pragma unroll
    for (int off = 1; off < 32; off <<= 1) part += __shfl_xor(part, off);
    if (tx == 0) scores_out[RM + mi] = part + bias2;
  }
}

// ---------------- topk: per-batch full bitonic sort of (descending score, ascending idx)
__global__ __launch_bounds__(1024) void topk_kernel(
    const float* __restrict__ scores, int k,
    float* __restrict__ idx_f, int* __restrict__ idx_i) {
  __shared__ unsigned long long keys[Lk];  // 64 KB
  const int b = blockIdx.x, t = threadIdx.x;
  for (int i = t; i < Lk; i += 1024) {
    unsigned u = __float_as_uint(scores[(size_t)b * Lk + i]);
    unsigned mono = (u & 0x80000000u) ? ~u : (u | 0x80000000u);  // ascending in value
    keys[i] = ((unsigned long long)(~mono) << 32) | (unsigned)i; // asc sort => desc score, asc idx
  }
  __syncthreads();
  for (int size = 2; size <= Lk; size <<= 1) {
    for (int stride = size >> 1; stride > 0; stride >>= 1) {
      for (int p = t; p < Lk / 2; p += 1024) {
        int lo = ((p & ~(stride - 1)) << 1) | (p & (stride - 1));
        int hi = lo + stride;
        bool up = ((lo & size) == 0);
        unsigned long long a = keys[lo], c = keys[hi];
        if ((a > c) == up) { keys[lo] = c; keys[hi] = a; }
      }
      __syncthreads();
    }
  }
  for (int i = t; i < k; i += 1024) {
    int id = (int)(keys[i] & 0xFFFFFFFFu);
    idx_f[(size_t)b * k + i] = (float)id;  // out buffer is fp32; indices exact in fp32
    idx_i[(size_t)b * k + i] = id;
  }
}

// ---------------- gather: one block per selected row, 4 KB float4 copy
__global__ __launch_bounds__(256) void gather_kernel(
    const float* __restrict__ F, const int* __restrict__ idx,
    float* __restrict__ out, int k) {
  int row = blockIdx.x;          // 0 .. 8*k-1
  int b = row / k;
  int id = idx[row];
  const float4* src = reinterpret_cast<const float4*>(F + ((size_t)b * Lk + id) * Dk);
  float4* dst = reinterpret_cast<float4*>(out + (size_t)row * Dk);
  dst[threadIdx.x] = src[threadIdx.x];
}

extern "C" void kernel_launch(void* const* d_in, const int* in_sizes, int n_in,
                              void* d_out, int out_size, void* d_ws, size_t ws_size,
                              hipStream_t stream) {
  const float* F     = (const float*)d_in[0];
  const float* gamma = (const float*)d_in[1];
  const float* beta  = (const float*)d_in[2];
  const float* W1    = (const float*)d_in[3];
  const float* b1    = (const float*)d_in[4];
  const float* W2    = (const float*)d_in[5];
  const float* b2    = (const float*)d_in[6];
  // k lives on device; derive on host from out_size = 8*k*1024 + 8*8192 + 8*k
  int k = (out_size - Bk * Lk) / (Bk * Dk + Bk);   // = 512

  float* out_sel = (float*)d_out;                       // [8, k, 1024]
  float* out_sc  = out_sel + (size_t)Bk * k * Dk;       // [8, 8192]
  float* out_idx = out_sc + (size_t)Bk * Lk;            // [8, k] as float

  float* S    = (float*)d_ws;
  float* Tb   = S + Hk;
  int*   idxi = (int*)(Tb + Hk);

  hipLaunchKernelGGL(prep_kernel,   dim3(1),          dim3(Hk),   0, stream,
                     gamma, beta, W1, b1, S, Tb);
  hipLaunchKernelGGL(scores_kernel, dim3(MTOT / 128), dim3(512),  0, stream,
                     F, gamma, W1, S, Tb, W2, b2, out_sc);
  hipLaunchKernelGGL(topk_kernel,   dim3(Bk),         dim3(1024), 0, stream,
                     out_sc, k, out_idx, idxi);
  hipLaunchKernelGGL(gather_kernel, dim3(Bk * k),     dim3(256),  0, stream,
                     F, idxi, out_sel, k);
}

// Round 3
// 2472.700 us; speedup vs baseline: 3.9264x; 3.9264x over previous
//
#include <hip/hip_runtime.h>
#include <math.h>

#define Dk 1024
#define Hk 256
#define Lk 8192
#define Bk 8
#define MTOT (Bk*Lk)   // 65536 rows

typedef float f32x2 __attribute__((ext_vector_type(2)));

// ---------------- prep: S[j] = sum_d gamma[d]*W1[d][j], Tb[j] = sum_d beta[d]*W1[d][j] + b1[j]
__global__ __launch_bounds__(256) void prep_kernel(
    const float* __restrict__ gamma, const float* __restrict__ beta,
    const float* __restrict__ W1, const float* __restrict__ b1,
    float* __restrict__ S, float* __restrict__ Tb) {
  int j = threadIdx.x;  // 0..255
  float s = 0.f, t = 0.f;
  for (int d = 0; d < Dk; ++d) {
    float w = W1[d * Hk + j];
    s = fmaf(gamma[d], w, s);
    t = fmaf(beta[d], w, t);
  }
  S[j] = s;
  Tb[j] = t + b1[j];
}

// ---------------- scores: fused LN + Linear(1024->256) + GELU + Linear(256->1)
// Packed-fp32 (v_pk_fma_f32) microtile, LDS double-buffered (1 barrier/tile).
// __launch_bounds__(512,2): under hipcc's observed CUDA-style reading (min
// 2 blocks/CU = 4 waves/SIMD) this caps VGPR at 128 — fits the ~120-reg
// kernel with NO spill. (512,4) capped at 64 and spilled the accumulators
// to scratch (round-2: 31 GB scratch traffic, 20x regression).
__global__ __launch_bounds__(512, 2) void scores_kernel(
    const float* __restrict__ F, const float* __restrict__ gamma,
    const float* __restrict__ W1,
    const float* __restrict__ S, const float* __restrict__ Tb,
    const float* __restrict__ W2, const float* __restrict__ b2,
    float* __restrict__ scores_out) {
  __shared__ float As[2][16][132];   // k-major, +4 pad
  __shared__ float Bs[2][16][256];
  __shared__ float smu[128];
  __shared__ float srs[128];

  const int tid = threadIdx.x;
  const int tx = tid & 31;        // n dimension (32 lanes)
  const int ty = tid >> 5;        // m dimension (16)
  const int RM = blockIdx.x * 128;

  // staging indices
  const int ar  = tid >> 2;        // A row 0..127
  const int akq = (tid & 3) * 4;   // A k sub-offset {0,4,8,12}
  const int bk  = tid >> 5;        // B k row 0..15
  const int bn  = (tid & 31) * 8;  // B n offset

  const float* Aptr = F + (size_t)(RM + ar) * Dk + akq;

  float4 av, bv0, bv1, gv;
  av  = *reinterpret_cast<const float4*>(Aptr);
  bv0 = *reinterpret_cast<const float4*>(W1 + (size_t)bk * Hk + bn);
  bv1 = *reinterpret_cast<const float4*>(W1 + (size_t)bk * Hk + bn + 4);
  gv  = *reinterpret_cast<const float4*>(gamma + akq);

  f32x2 acc2[8][4];
  #pragma unroll
  for (int i = 0; i < 8; ++i)
    #pragma unroll
    for (int j = 0; j < 4; ++j) acc2[i][j] = (f32x2){0.f, 0.f};

  float rsum = 0.f, rsq = 0.f;

  // ---- stage tile 0 into buffer 0 (stats for tile 0, same fp order as before)
  rsum += av.x + av.y + av.z + av.w;
  rsq = fmaf(av.x, av.x, fmaf(av.y, av.y, fmaf(av.z, av.z, fmaf(av.w, av.w, rsq))));
  As[0][akq + 0][ar] = av.x * gv.x;
  As[0][akq + 1][ar] = av.y * gv.y;
  As[0][akq + 2][ar] = av.z * gv.z;
  As[0][akq + 3][ar] = av.w * gv.w;
  *reinterpret_cast<float4*>(&Bs[0][bk][bn])     = bv0;
  *reinterpret_cast<float4*>(&Bs[0][bk][bn + 4]) = bv1;

  for (int s = 0; s < Dk / 16; ++s) {
    __syncthreads();  // tile s visible; everyone done reading buffer s^1
    const int cur = s & 1;
    float (*Ac)[132] = As[cur];
    float (*Bc)[256] = Bs[cur];
    if (s + 1 < Dk / 16) {  // prefetch tile s+1 into regs (hides under compute)
      av  = *reinterpret_cast<const float4*>(Aptr + (s + 1) * 16);
      bv0 = *reinterpret_cast<const float4*>(W1 + (size_t)((s + 1) * 16 + bk) * Hk + bn);
      bv1 = *reinterpret_cast<const float4*>(W1 + (size_t)((s + 1) * 16 + bk) * Hk + bn + 4);
      gv  = *reinterpret_cast<const float4*>(gamma + (s + 1) * 16 + akq);
    }
    #pragma unroll
    for (int kk = 0; kk < 16; ++kk) {
      const float4 a0 = *reinterpret_cast<const float4*>(&Ac[kk][ty * 4]);
      const float4 a1 = *reinterpret_cast<const float4*>(&Ac[kk][ty * 4 + 64]);
      const float4 b0 = *reinterpret_cast<const float4*>(&Bc[kk][tx * 4]);
      const float4 b1 = *reinterpret_cast<const float4*>(&Bc[kk][tx * 4 + 128]);
      const f32x2 bb[4] = {{b0.x, b0.y}, {b0.z, b0.w}, {b1.x, b1.y}, {b1.z, b1.w}};
      const float aa[8] = {a0.x, a0.y, a0.z, a0.w, a1.x, a1.y, a1.z, a1.w};
      #pragma unroll
      for (int i = 0; i < 8; ++i) {
        const f32x2 ai = {aa[i], aa[i]};
        #pragma unroll
        for (int jp = 0; jp < 4; ++jp)
          acc2[i][jp] = __builtin_elementwise_fma(ai, bb[jp], acc2[i][jp]);
      }
    }
    if (s + 1 < Dk / 16) {  // stats (tile order 0..63 preserved) + stage into buffer s+1
      rsum += av.x + av.y + av.z + av.w;
      rsq = fmaf(av.x, av.x, fmaf(av.y, av.y, fmaf(av.z, av.z, fmaf(av.w, av.w, rsq))));
      const int nxt = cur ^ 1;
      As[nxt][akq + 0][ar] = av.x * gv.x;
      As[nxt][akq + 1][ar] = av.y * gv.y;
      As[nxt][akq + 2][ar] = av.z * gv.z;
      As[nxt][akq + 3][ar] = av.w * gv.w;
      *reinterpret_cast<float4*>(&Bs[nxt][bk][bn])     = bv0;
      *reinterpret_cast<float4*>(&Bs[nxt][bk][bn + 4]) = bv1;
    }
  }

  // finish row stats: threads 4r..4r+3 each hold a quarter of row r
  rsum += __shfl_xor(rsum, 1); rsum += __shfl_xor(rsum, 2);
  rsq  += __shfl_xor(rsq, 1);  rsq  += __shfl_xor(rsq, 2);
  if ((tid & 3) == 0) {
    float mu  = rsum * (1.f / 1024.f);
    float var = rsq * (1.f / 1024.f) - mu * mu;
    smu[ar] = mu;
    srs[ar] = rsqrtf(var + 1e-5f);
  }
  __syncthreads();

  // epilogue: LN affine + GELU(exact) + dot with W2, half-wave reduce over n
  float sj[8], tbj[8], w2j[8];
  #pragma unroll
  for (int j = 0; j < 8; ++j) {
    int nj = tx * 4 + (j < 4 ? j : 124 + j);
    sj[j] = S[nj]; tbj[j] = Tb[nj]; w2j[j] = W2[nj];
  }
  const float bias2 = b2[0];
  #pragma unroll
  for (int i = 0; i < 8; ++i) {
    int mi = ty * 4 + (i < 4 ? i : 60 + i);
    float mu = smu[mi], rs = srs[mi];
    float part = 0.f;
    #pragma unroll
    for (int j = 0; j < 8; ++j) {
      float hpre = rs * acc2[i][j >> 1][j & 1] - rs * mu * sj[j] + tbj[j];
      float h = 0.5f * hpre * (1.f + erff(hpre * 0.70710678118654752f));
      part = fmaf(h, w2j[j], part);
    }
    #pragma unroll
    for (int off = 1; off < 32; off <<= 1) part += __shfl_xor(part, off);
    if (tx == 0) scores_out[RM + mi] = part + bias2;
  }
}

// ---------------- topk: per-batch full bitonic sort of (descending score, ascending idx)
__global__ __launch_bounds__(1024) void topk_kernel(
    const float* __restrict__ scores, int k,
    float* __restrict__ idx_f, int* __restrict__ idx_i) {
  __shared__ unsigned long long keys[Lk];  // 64 KB
  const int b = blockIdx.x, t = threadIdx.x;
  for (int i = t; i < Lk; i += 1024) {
    unsigned u = __float_as_uint(scores[(size_t)b * Lk + i]);
    unsigned mono = (u & 0x80000000u) ? ~u : (u | 0x80000000u);  // ascending in value
    keys[i] = ((unsigned long long)(~mono) << 32) | (unsigned)i; // asc sort => desc score, asc idx
  }
  __syncthreads();
  for (int size = 2; size <= Lk; size <<= 1) {
    for (int stride = size >> 1; stride > 0; stride >>= 1) {
      for (int p = t; p < Lk / 2; p += 1024) {
        int lo = ((p & ~(stride - 1)) << 1) | (p & (stride - 1));
        int hi = lo + stride;
        bool up = ((lo & size) == 0);
        unsigned long long a = keys[lo], c = keys[hi];
        if ((a > c) == up) { keys[lo] = c; keys[hi] = a; }
      }
      __syncthreads();
    }
  }
  for (int i = t; i < k; i += 1024) {
    int id = (int)(keys[i] & 0xFFFFFFFFu);
    idx_f[(size_t)b * k + i] = (float)id;  // out buffer is fp32; indices exact in fp32
    idx_i[(size_t)b * k + i] = id;
  }
}

// ---------------- gather: one block per selected row, 4 KB float4 copy
__global__ __launch_bounds__(256) void gather_kernel(
    const float* __restrict__ F, const int* __restrict__ idx,
    float* __restrict__ out, int k) {
  int row = blockIdx.x;          // 0 .. 8*k-1
  int b = row / k;
  int id = idx[row];
  const float4* src = reinterpret_cast<const float4*>(F + ((size_t)b * Lk + id) * Dk);
  float4* dst = reinterpret_cast<float4*>(out + (size_t)row * Dk);
  dst[threadIdx.x] = src[threadIdx.x];
}

extern "C" void kernel_launch(void* const* d_in, const int* in_sizes, int n_in,
                              void* d_out, int out_size, void* d_ws, size_t ws_size,
                              hipStream_t stream) {
  const float* F     = (const float*)d_in[0];
  const float* gamma = (const float*)d_in[1];
  const float* beta  = (const float*)d_in[2];
  const float* W1    = (const float*)d_in[3];
  const float* b1    = (const float*)d_in[4];
  const float* W2    = (const float*)d_in[5];
  const float* b2    = (const float*)d_in[6];
  // k lives on device; derive on host from out_size = 8*k*1024 + 8*8192 + 8*k
  int k = (out_size - Bk * Lk) / (Bk * Dk + Bk);   // = 512

  float* out_sel = (float*)d_out;                       // [8, k, 1024]
  float* out_sc  = out_sel + (size_t)Bk * k * Dk;       // [8, 8192]
  float* out_idx = out_sc + (size_t)Bk * Lk;            // [8, k] as float

  float* S    = (float*)d_ws;
  float* Tb   = S + Hk;
  int*   idxi = (int*)(Tb + Hk);

  hipLaunchKernelGGL(prep_kernel,   dim3(1),          dim3(Hk),   0, stream,
                     gamma, beta, W1, b1, S, Tb);
  hipLaunchKernelGGL(scores_kernel, dim3(MTOT / 128), dim3(512),  0, stream,
                     F, gamma, W1, S, Tb, W2, b2, out_sc);
  hipLaunchKernelGGL(topk_kernel,   dim3(Bk),         dim3(1024), 0, stream,
                     out_sc, k, out_idx, idxi);
  hipLaunchKernelGGL(gather_kernel, dim3(Bk * k),     dim3(256),  0, stream,
                     F, idxi, out_sel, k);
}

// Round 4
// 499.682 us; speedup vs baseline: 19.4301x; 4.9485x over previous
//
#include <hip/hip_runtime.h>
#include <math.h>

#define Dk 1024
#define Hk 256
#define Lk 8192
#define Bk 8
#define MTOT (Bk*Lk)   // 65536 rows

typedef float f32x2 __attribute__((ext_vector_type(2)));

// ---------------- prep: S[j] = sum_d gamma[d]*W1[d][j], Tb[j] = sum_d beta[d]*W1[d][j] + b1[j]
__global__ __launch_bounds__(256) void prep_kernel(
    const float* __restrict__ gamma, const float* __restrict__ beta,
    const float* __restrict__ W1, const float* __restrict__ b1,
    float* __restrict__ S, float* __restrict__ Tb) {
  int j = threadIdx.x;  // 0..255
  float s = 0.f, t = 0.f;
  for (int d = 0; d < Dk; ++d) {
    float w = W1[d * Hk + j];
    s = fmaf(gamma[d], w, s);
    t = fmaf(beta[d], w, t);
  }
  S[j] = s;
  Tb[j] = t + b1[j];
}

// ---------------- scores: fused LN + Linear(1024->256) + GELU + Linear(256->1)
// Round-1 structure (single LDS buffer, 2 barriers/tile, 116-reg no-spill)
// with ONLY the accumulators packed as f32x2 -> v_pk_fma_f32 (2 FMA/issue).
// Packing is across independent output columns j,j+1: each accumulator's
// sequential-k fp32 order is unchanged => bit-identical scores vs round 1.
// NO launch_bounds min: (512,4)/(512,2) caps (64/128 regs, CUDA-style
// blocks/CU semantics observed in rounds 2-3) caused scratch spill.
__global__ __launch_bounds__(512) void scores_kernel(
    const float* __restrict__ F, const float* __restrict__ gamma,
    const float* __restrict__ W1,
    const float* __restrict__ S, const float* __restrict__ Tb,
    const float* __restrict__ W2, const float* __restrict__ b2,
    float* __restrict__ scores_out) {
  __shared__ float As[16][132];   // k-major, +4 pad: staging writes 2-way (free)
  __shared__ float Bs[16][256];
  __shared__ float smu[128];
  __shared__ float srs[128];

  const int tid = threadIdx.x;
  const int tx = tid & 31;        // n dimension (32 lanes)
  const int ty = tid >> 5;        // m dimension (16)
  const int RM = blockIdx.x * 128;

  // staging indices
  const int ar  = tid >> 2;        // A row 0..127
  const int akq = (tid & 3) * 4;   // A k sub-offset {0,4,8,12}
  const int bk  = tid >> 5;        // B k row 0..15
  const int bn  = (tid & 31) * 8;  // B n offset

  const float* Aptr = F + (size_t)(RM + ar) * Dk + akq;

  float4 av, bv0, bv1, gv;
  av  = *reinterpret_cast<const float4*>(Aptr);
  bv0 = *reinterpret_cast<const float4*>(W1 + (size_t)bk * Hk + bn);
  bv1 = *reinterpret_cast<const float4*>(W1 + (size_t)bk * Hk + bn + 4);
  gv  = *reinterpret_cast<const float4*>(gamma + akq);

  f32x2 acc2[8][4];
  #pragma unroll
  for (int i = 0; i < 8; ++i)
    #pragma unroll
    for (int j = 0; j < 4; ++j) acc2[i][j] = (f32x2){0.f, 0.f};

  float rsum = 0.f, rsq = 0.f;

  for (int s = 0; s < Dk / 16; ++s) {
    __syncthreads();  // previous compute done reading LDS
    // row stats on RAW values, then gamma-scale into LDS
    rsum += av.x + av.y + av.z + av.w;
    rsq = fmaf(av.x, av.x, fmaf(av.y, av.y, fmaf(av.z, av.z, fmaf(av.w, av.w, rsq))));
    As[akq + 0][ar] = av.x * gv.x;
    As[akq + 1][ar] = av.y * gv.y;
    As[akq + 2][ar] = av.z * gv.z;
    As[akq + 3][ar] = av.w * gv.w;
    *reinterpret_cast<float4*>(&Bs[bk][bn])     = bv0;
    *reinterpret_cast<float4*>(&Bs[bk][bn + 4]) = bv1;
    __syncthreads();
    if (s + 1 < Dk / 16) {  // register prefetch of next tile (hides under compute)
      av  = *reinterpret_cast<const float4*>(Aptr + (s + 1) * 16);
      bv0 = *reinterpret_cast<const float4*>(W1 + (size_t)((s + 1) * 16 + bk) * Hk + bn);
      bv1 = *reinterpret_cast<const float4*>(W1 + (size_t)((s + 1) * 16 + bk) * Hk + bn + 4);
      gv  = *reinterpret_cast<const float4*>(gamma + (s + 1) * 16 + akq);
    }
    #pragma unroll
    for (int kk = 0; kk < 16; ++kk) {
      const float4 a0 = *reinterpret_cast<const float4*>(&As[kk][ty * 4]);
      const float4 a1 = *reinterpret_cast<const float4*>(&As[kk][ty * 4 + 64]);
      const float4 b0 = *reinterpret_cast<const float4*>(&Bs[kk][tx * 4]);
      const float4 b1 = *reinterpret_cast<const float4*>(&Bs[kk][tx * 4 + 128]);
      const f32x2 bb[4] = {{b0.x, b0.y}, {b0.z, b0.w}, {b1.x, b1.y}, {b1.z, b1.w}};
      const float aa[8] = {a0.x, a0.y, a0.z, a0.w, a1.x, a1.y, a1.z, a1.w};
      #pragma unroll
      for (int i = 0; i < 8; ++i) {
        const f32x2 ai = {aa[i], aa[i]};   // expect VOP3P op_sel splat, no movs
        #pragma unroll
        for (int jp = 0; jp < 4; ++jp)
          acc2[i][jp] = __builtin_elementwise_fma(ai, bb[jp], acc2[i][jp]);
      }
    }
  }

  // finish row stats: threads 4r..4r+3 each hold a quarter of row r
  rsum += __shfl_xor(rsum, 1); rsum += __shfl_xor(rsum, 2);
  rsq  += __shfl_xor(rsq, 1);  rsq  += __shfl_xor(rsq, 2);
  if ((tid & 3) == 0) {
    float mu  = rsum * (1.f / 1024.f);
    float var = rsq * (1.f / 1024.f) - mu * mu;
    smu[ar] = mu;
    srs[ar] = rsqrtf(var + 1e-5f);
  }
  __syncthreads();

  // epilogue: LN affine + GELU(exact) + dot with W2, half-wave reduce over n
  float sj[8], tbj[8], w2j[8];
  #pragma unroll
  for (int j = 0; j < 8; ++j) {
    int nj = tx * 4 + (j < 4 ? j : 124 + j);
    sj[j] = S[nj]; tbj[j] = Tb[nj]; w2j[j] = W2[nj];
  }
  const float bias2 = b2[0];
  #pragma unroll
  for (int i = 0; i < 8; ++i) {
    int mi = ty * 4 + (i < 4 ? i : 60 + i);
    float mu = smu[mi], rs = srs[mi];
    float part = 0.f;
    #pragma unroll
    for (int j = 0; j < 8; ++j) {
      float hpre = rs * acc2[i][j >> 1][j & 1] - rs * mu * sj[j] + tbj[j];
      float h = 0.5f * hpre * (1.f + erff(hpre * 0.70710678118654752f));
      part = fmaf(h, w2j[j], part);
    }
    #pragma unroll
    for (int off = 1; off < 32; off <<= 1) part += __shfl_xor(part, off);
    if (tx == 0) scores_out[RM + mi] = part + bias2;
  }
}

// ---------------- topk: per-batch full bitonic sort of (descending score, ascending idx)
__global__ __launch_bounds__(1024) void topk_kernel(
    const float* __restrict__ scores, int k,
    float* __restrict__ idx_f, int* __restrict__ idx_i) {
  __shared__ unsigned long long keys[Lk];  // 64 KB
  const int b = blockIdx.x, t = threadIdx.x;
  for (int i = t; i < Lk; i += 1024) {
    unsigned u = __float_as_uint(scores[(size_t)b * Lk + i]);
    unsigned mono = (u & 0x80000000u) ? ~u : (u | 0x80000000u);  // ascending in value
    keys[i] = ((unsigned long long)(~mono) << 32) | (unsigned)i; // asc sort => desc score, asc idx
  }
  __syncthreads();
  for (int size = 2; size <= Lk; size <<= 1) {
    for (int stride = size >> 1; stride > 0; stride >>= 1) {
      for (int p = t; p < Lk / 2; p += 1024) {
        int lo = ((p & ~(stride - 1)) << 1) | (p & (stride - 1));
        int hi = lo + stride;
        bool up = ((lo & size) == 0);
        unsigned long long a = keys[lo], c = keys[hi];
        if ((a > c) == up) { keys[lo] = c; keys[hi] = a; }
      }
      __syncthreads();
    }
  }
  for (int i = t; i < k; i += 1024) {
    int id = (int)(keys[i] & 0xFFFFFFFFu);
    idx_f[(size_t)b * k + i] = (float)id;  // out buffer is fp32; indices exact in fp32
    idx_i[(size_t)b * k + i] = id;
  }
}

// ---------------- gather: one block per selected row, 4 KB float4 copy
__global__ __launch_bounds__(256) void gather_kernel(
    const float* __restrict__ F, const int* __restrict__ idx,
    float* __restrict__ out, int k) {
  int row = blockIdx.x;          // 0 .. 8*k-1
  int b = row / k;
  int id = idx[row];
  const float4* src = reinterpret_cast<const float4*>(F + ((size_t)b * Lk + id) * Dk);
  float4* dst = reinterpret_cast<float4*>(out + (size_t)row * Dk);
  dst[threadIdx.x] = src[threadIdx.x];
}

extern "C" void kernel_launch(void* const* d_in, const int* in_sizes, int n_in,
                              void* d_out, int out_size, void* d_ws, size_t ws_size,
                              hipStream_t stream) {
  const float* F     = (const float*)d_in[0];
  const float* gamma = (const float*)d_in[1];
  const float* beta  = (const float*)d_in[2];
  const float* W1    = (const float*)d_in[3];
  const float* b1    = (const float*)d_in[4];
  const float* W2    = (const float*)d_in[5];
  const float* b2    = (const float*)d_in[6];
  // k lives on device; derive on host from out_size = 8*k*1024 + 8*8192 + 8*k
  int k = (out_size - Bk * Lk) / (Bk * Dk + Bk);   // = 512

  float* out_sel = (float*)d_out;                       // [8, k, 1024]
  float* out_sc  = out_sel + (size_t)Bk * k * Dk;       // [8, 8192]
  float* out_idx = out_sc + (size_t)Bk * Lk;            // [8, k] as float

  float* S    = (float*)d_ws;
  float* Tb   = S + Hk;
  int*   idxi = (int*)(Tb + Hk);

  hipLaunchKernelGGL(prep_kernel,   dim3(1),          dim3(Hk),   0, stream,
                     gamma, beta, W1, b1, S, Tb);
  hipLaunchKernelGGL(scores_kernel, dim3(MTOT / 128), dim3(512),  0, stream,
                     F, gamma, W1, S, Tb, W2, b2, out_sc);
  hipLaunchKernelGGL(topk_kernel,   dim3(Bk),         dim3(1024), 0, stream,
                     out_sc, k, out_idx, idxi);
  hipLaunchKernelGGL(gather_kernel, dim3(Bk * k),     dim3(256),  0, stream,
                     F, idxi, out_sel, k);
}

// Round 5
// 355.725 us; speedup vs baseline: 27.2932x; 1.4047x over previous
//
#include <hip/hip_runtime.h>
#include <math.h>

#define Dk 1024
#define Hk 256
#define Lk 8192
#define Bk 8
#define MTOT (Bk*Lk)   // 65536 rows

typedef __bf16 bf16;
typedef __attribute__((ext_vector_type(8))) __bf16 bf16x8;
typedef __attribute__((ext_vector_type(4))) __bf16 bf16x4;
typedef __attribute__((ext_vector_type(4))) float f32x4;

// ---------------- prep: S[j] = sum_d gamma[d]*W1[d][j], Tb[j] = sum_d beta[d]*W1[d][j] + b1[j]
__global__ __launch_bounds__(256) void prep_kernel(
    const float* __restrict__ gamma, const float* __restrict__ beta,
    const float* __restrict__ W1, const float* __restrict__ b1,
    float* __restrict__ S, float* __restrict__ Tb) {
  int j = threadIdx.x;  // 0..255
  float s = 0.f, t = 0.f;
  for (int d = 0; d < Dk; ++d) {
    float w = W1[d * Hk + j];
    s = fmaf(gamma[d], w, s);
    t = fmaf(beta[d], w, t);
  }
  S[j] = s;
  Tb[j] = t + b1[j];
}

// ---------------- prep_split: W1 -> 3-way bf16 split in MFMA-fragment order.
// Layout: W1F[ks(32)][sp(3)][nf(16)][kg(4)][n(16)][k(8)] bf16, where
// d = ks*32 + kg*8 + k, h = nf*16 + n. Per-K-step block = 24576 elems (48KB),
// contiguous -> scores kernel stages B with plain 16B copies.
__global__ __launch_bounds__(1024) void prep_split(
    const float* __restrict__ W1, bf16* __restrict__ W1F) {
  for (int idx = threadIdx.x + blockIdx.x * 1024; idx < Dk * Hk;
       idx += gridDim.x * 1024) {
    int d = idx >> 8, h = idx & 255;
    float w = W1[idx];
    bf16 hi = (bf16)w;  float r1 = w - (float)hi;
    bf16 mi = (bf16)r1; float r2 = r1 - (float)mi;
    bf16 lo = (bf16)r2;
    int ks = d >> 5, kg = (d >> 3) & 3, kk = d & 7;
    int nf = h >> 4, nn = h & 15;
    size_t base = (((size_t)ks * 3 * 16 + nf) * 4 + kg) * 128 + nn * 8 + kk;
    const size_t spStride = 16 * 4 * 128;  // 8192 elems per split per K-step
    W1F[base] = hi;
    W1F[base + spStride] = mi;
    W1F[base + 2 * spStride] = lo;
  }
}

// ---------------- scores: fused LN + Linear(1024->256) + GELU + Linear(256->1)
// GEMM via 3-way-split bf16 MFMA (6 products: hh,hm,mh,mm,hl,lh -> error
// ~2^-26 rel, far below the ~5e-4 rank-512 score spacing => identical top-k).
// LN folded: hpre = rs*acc - rs*mu*S[j] + Tb[j]; stats fp32 during staging.
// 1024 thr = 16 waves (2M x 8N, wave tile 64x32), BM=128, BN=256, BK=32.
__global__ __launch_bounds__(1024) void scores_mfma(
    const float* __restrict__ F, const float* __restrict__ gamma,
    const bf16* __restrict__ W1F,
    const float* __restrict__ S, const float* __restrict__ Tb,
    const float* __restrict__ W2, const float* __restrict__ b2,
    float* __restrict__ scores_out) {
  __shared__ bf16 As[3 * 4 * 128 * 8];    // 24KB [sp][kg][row][k8]
  __shared__ bf16 Bs[3 * 16 * 4 * 128];   // 48KB [sp][nf][kg][n16*k8]
  __shared__ float smu[128], srs[128];
  __shared__ float sred[128][8];

  const int tid = threadIdx.x;
  const int RM = blockIdx.x * 128;
  const int wid = tid >> 6, lane = tid & 63;
  const int wm = wid & 1, wn = wid >> 1;     // wn 0..7 (32-col slice)
  const int lg = lane >> 4, l15 = lane & 15;

  // A staging: thread -> (row, k-quarter of 4 elems)
  const int arow = tid >> 3, akq = tid & 7;
  const float* Aptr = F + (size_t)(RM + arow) * Dk + akq * 4;

  f32x4 acc[4][2];
  #pragma unroll
  for (int i = 0; i < 4; ++i)
    #pragma unroll
    for (int j = 0; j < 2; ++j) acc[i][j] = (f32x4){0.f, 0.f, 0.f, 0.f};

  float rsum = 0.f, rsq = 0.f;

  for (int s = 0; s < Dk / 32; ++s) {
    // ---- stage A: load 4 fp32, stats, gamma-scale, 3-way split, b64 writes
    float4 av = *reinterpret_cast<const float4*>(Aptr + s * 32);
    float4 gv = *reinterpret_cast<const float4*>(gamma + s * 32 + akq * 4);
    rsum += av.x + av.y + av.z + av.w;
    rsq = fmaf(av.x, av.x, fmaf(av.y, av.y, fmaf(av.z, av.z, fmaf(av.w, av.w, rsq))));
    float x0 = av.x * gv.x, x1 = av.y * gv.y, x2 = av.z * gv.z, x3 = av.w * gv.w;
    bf16 h0 = (bf16)x0, h1 = (bf16)x1, h2 = (bf16)x2, h3 = (bf16)x3;
    float r0 = x0 - (float)h0, r1 = x1 - (float)h1, r2 = x2 - (float)h2, r3 = x3 - (float)h3;
    bf16 m0 = (bf16)r0, m1 = (bf16)r1, m2 = (bf16)r2, m3 = (bf16)r3;
    bf16 l0 = (bf16)(r0 - (float)m0), l1 = (bf16)(r1 - (float)m1);
    bf16 l2 = (bf16)(r2 - (float)m2), l3 = (bf16)(r3 - (float)m3);
    const int kg = akq >> 1, joff = (akq & 1) * 4;
    const int abase = kg * 128 * 8 + arow * 8 + joff;
    *reinterpret_cast<bf16x4*>(&As[abase])                 = (bf16x4){h0, h1, h2, h3};
    *reinterpret_cast<bf16x4*>(&As[abase + 4 * 128 * 8])   = (bf16x4){m0, m1, m2, m3};
    *reinterpret_cast<bf16x4*>(&As[abase + 8 * 128 * 8])   = (bf16x4){l0, l1, l2, l3};
    // ---- stage B: 3 x 16B contiguous copies (pre-formatted by prep_split)
    const bf16* Bsrc = W1F + (size_t)s * 24576;
    #pragma unroll
    for (int c = 0; c < 3; ++c) {
      int cid = tid + c * 1024;
      *reinterpret_cast<bf16x8*>(&Bs[cid * 8]) =
          *reinterpret_cast<const bf16x8*>(&Bsrc[(size_t)cid * 8]);
    }
    __syncthreads();
    // ---- MFMA: wave tile 64x32 = 4 mfrag x 2 nfrag, 6 products each
    bf16x8 bfr[2][3];
    #pragma unroll
    for (int nf = 0; nf < 2; ++nf)
      #pragma unroll
      for (int sp = 0; sp < 3; ++sp)
        bfr[nf][sp] = *reinterpret_cast<const bf16x8*>(
            &Bs[((sp * 16 + (wn * 2 + nf)) * 4 + lg) * 128 + l15 * 8]);
    #pragma unroll
    for (int mf = 0; mf < 4; ++mf) {
      bf16x8 afr[3];
      #pragma unroll
      for (int sp = 0; sp < 3; ++sp)
        afr[sp] = *reinterpret_cast<const bf16x8*>(
            &As[(sp * 4 + lg) * 128 * 8 + (wm * 64 + mf * 16 + l15) * 8]);
      #pragma unroll
      for (int nf = 0; nf < 2; ++nf) {
        f32x4 a = acc[mf][nf];
        a = __builtin_amdgcn_mfma_f32_16x16x32_bf16(afr[0], bfr[nf][0], a, 0, 0, 0);
        a = __builtin_amdgcn_mfma_f32_16x16x32_bf16(afr[0], bfr[nf][1], a, 0, 0, 0);
        a = __builtin_amdgcn_mfma_f32_16x16x32_bf16(afr[1], bfr[nf][0], a, 0, 0, 0);
        a = __builtin_amdgcn_mfma_f32_16x16x32_bf16(afr[1], bfr[nf][1], a, 0, 0, 0);
        a = __builtin_amdgcn_mfma_f32_16x16x32_bf16(afr[0], bfr[nf][2], a, 0, 0, 0);
        a = __builtin_amdgcn_mfma_f32_16x16x32_bf16(afr[2], bfr[nf][0], a, 0, 0, 0);
        acc[mf][nf] = a;
      }
    }
    __syncthreads();
  }

  // finish stats: row owned by 8 lanes (tid&7)
  rsum += __shfl_xor(rsum, 1); rsum += __shfl_xor(rsum, 2); rsum += __shfl_xor(rsum, 4);
  rsq  += __shfl_xor(rsq, 1);  rsq  += __shfl_xor(rsq, 2);  rsq  += __shfl_xor(rsq, 4);
  if ((tid & 7) == 0) {
    float mu  = rsum * (1.f / 1024.f);
    float var = rsq * (1.f / 1024.f) - mu * mu;
    smu[arow] = mu;
    srs[arow] = rsqrtf(var + 1e-5f);
  }
  __syncthreads();

  // epilogue: C/D layout col=l15, row=lg*4+reg (HW-verified). LN affine +
  // GELU(exact) + W2 dot; 16-lane reduce; cross-wave via sred (fixed order).
  float s2[2], tb2[2], w2v[2];
  #pragma unroll
  for (int nf = 0; nf < 2; ++nf) {
    int col = wn * 32 + nf * 16 + l15;
    s2[nf] = S[col]; tb2[nf] = Tb[col]; w2v[nf] = W2[col];
  }
  #pragma unroll
  for (int mf = 0; mf < 4; ++mf) {
    const int rbase = wm * 64 + mf * 16 + lg * 4;
    #pragma unroll
    for (int reg = 0; reg < 4; ++reg) {
      const int row = rbase + reg;
      float mu = smu[row], rs = srs[row];
      float part = 0.f;
      #pragma unroll
      for (int nf = 0; nf < 2; ++nf) {
        float hpre = rs * acc[mf][nf][reg] - rs * mu * s2[nf] + tb2[nf];
        float g = 0.5f * hpre * (1.f + erff(hpre * 0.70710678118654752f));
        part = fmaf(g, w2v[nf], part);
      }
      part += __shfl_xor(part, 1); part += __shfl_xor(part, 2);
      part += __shfl_xor(part, 4); part += __shfl_xor(part, 8);
      if (l15 == 0) sred[row][wn] = part;
    }
  }
  __syncthreads();
  if (tid < 128) {
    float sc = b2[0];
    #pragma unroll
    for (int w = 0; w < 8; ++w) sc += sred[tid][w];
    scores_out[RM + tid] = sc;
  }
}

// ---------------- topk: per-batch full bitonic sort of (descending score, ascending idx)
__global__ __launch_bounds__(1024) void topk_kernel(
    const float* __restrict__ scores, int k,
    float* __restrict__ idx_f, int* __restrict__ idx_i) {
  __shared__ unsigned long long keys[Lk];  // 64 KB
  const int b = blockIdx.x, t = threadIdx.x;
  for (int i = t; i < Lk; i += 1024) {
    unsigned u = __float_as_uint(scores[(size_t)b * Lk + i]);
    unsigned mono = (u & 0x80000000u) ? ~u : (u | 0x80000000u);  // ascending in value
    keys[i] = ((unsigned long long)(~mono) << 32) | (unsigned)i; // asc sort => desc score, asc idx
  }
  __syncthreads();
  for (int size = 2; size <= Lk; size <<= 1) {
    for (int stride = size >> 1; stride > 0; stride >>= 1) {
      for (int p = t; p < Lk / 2; p += 1024) {
        int lo = ((p & ~(stride - 1)) << 1) | (p & (stride - 1));
        int hi = lo + stride;
        bool up = ((lo & size) == 0);
        unsigned long long a = keys[lo], c = keys[hi];
        if ((a > c) == up) { keys[lo] = c; keys[hi] = a; }
      }
      __syncthreads();
    }
  }
  for (int i = t; i < k; i += 1024) {
    int id = (int)(keys[i] & 0xFFFFFFFFu);
    idx_f[(size_t)b * k + i] = (float)id;  // out buffer is fp32; indices exact in fp32
    idx_i[(size_t)b * k + i] = id;
  }
}

// ---------------- gather: one block per selected row, 4 KB float4 copy
__global__ __launch_bounds__(256) void gather_kernel(
    const float* __restrict__ F, const int* __restrict__ idx,
    float* __restrict__ out, int k) {
  int row = blockIdx.x;          // 0 .. 8*k-1
  int b = row / k;
  int id = idx[row];
  const float4* src = reinterpret_cast<const float4*>(F + ((size_t)b * Lk + id) * Dk);
  float4* dst = reinterpret_cast<float4*>(out + (size_t)row * Dk);
  dst[threadIdx.x] = src[threadIdx.x];
}

extern "C" void kernel_launch(void* const* d_in, const int* in_sizes, int n_in,
                              void* d_out, int out_size, void* d_ws, size_t ws_size,
                              hipStream_t stream) {
  const float* F     = (const float*)d_in[0];
  const float* gamma = (const float*)d_in[1];
  const float* beta  = (const float*)d_in[2];
  const float* W1    = (const float*)d_in[3];
  const float* b1    = (const float*)d_in[4];
  const float* W2    = (const float*)d_in[5];
  const float* b2    = (const float*)d_in[6];
  // k lives on device; derive on host from out_size = 8*k*1024 + 8*8192 + 8*k
  int k = (out_size - Bk * Lk) / (Bk * Dk + Bk);   // = 512

  float* out_sel = (float*)d_out;                       // [8, k, 1024]
  float* out_sc  = out_sel + (size_t)Bk * k * Dk;       // [8, 8192]
  float* out_idx = out_sc + (size_t)Bk * Lk;            // [8, k] as float

  // ws: W1F bf16[786432] (1.5MB), then S, Tb, idxi
  bf16*  W1F  = (bf16*)d_ws;
  float* Sp   = (float*)((char*)d_ws + 786432 * sizeof(bf16));
  float* Tbp  = Sp + Hk;
  int*   idxi = (int*)(Tbp + Hk);

  hipLaunchKernelGGL(prep_kernel,  dim3(1),          dim3(Hk),   0, stream,
                     gamma, beta, W1, b1, Sp, Tbp);
  hipLaunchKernelGGL(prep_split,   dim3(32),         dim3(1024), 0, stream,
                     W1, W1F);
  hipLaunchKernelGGL(scores_mfma,  dim3(MTOT / 128), dim3(1024), 0, stream,
                     F, gamma, W1F, Sp, Tbp, W2, b2, out_sc);
  hipLaunchKernelGGL(topk_kernel,  dim3(Bk),         dim3(1024), 0, stream,
                     out_sc, k, out_idx, idxi);
  hipLaunchKernelGGL(gather_kernel, dim3(Bk * k),    dim3(256),  0, stream,
                     F, idxi, out_sel, k);
}

// Round 6
// 265.071 us; speedup vs baseline: 36.6276x; 1.3420x over previous
//
#include <hip/hip_runtime.h>
#include <math.h>

#define Dk 1024
#define Hk 256
#define Lk 8192
#define Bk 8
#define MTOT (Bk*Lk)   // 65536 rows

typedef __bf16 bf16;
typedef __attribute__((ext_vector_type(8))) __bf16 bf16x8;
typedef __attribute__((ext_vector_type(4))) __bf16 bf16x4;
typedef __attribute__((ext_vector_type(4))) float f32x4;

// async global->LDS, 16B per lane (lane-linear LDS dest required)
#define GLD_LDS16(g, l)                                                        \
  __builtin_amdgcn_global_load_lds(                                            \
      (const __attribute__((address_space(1))) unsigned int*)(g),              \
      (__attribute__((address_space(3))) unsigned int*)(l), 16, 0, 0)

// ---------------- prep_split: W1 -> 3-way bf16 split in MFMA-fragment order,
// PLUS deterministic partial sums for S = gamma@W1, T = beta@W1.
// Layout: W1F[ks(32)][sp(3)][nf(16)][kg(4)][n(16)][k(8)], d=ks*32+kg*8+k, h=nf*16+n.
// Block b covers idx = b*1024 + t + j*32768 (j<8) => h = t&255 fixed per thread.
__global__ __launch_bounds__(1024) void prep_split(
    const float* __restrict__ W1, const float* __restrict__ gamma,
    const float* __restrict__ beta, bf16* __restrict__ W1F,
    float* __restrict__ Spart, float* __restrict__ Tpart) {
  __shared__ float ps[1024], pt[1024];
  const int b = blockIdx.x, t = threadIdx.x;
  float sa = 0.f, ta = 0.f;
  #pragma unroll
  for (int j = 0; j < 8; ++j) {
    int idx = b * 1024 + t + j * 32768;
    int d = idx >> 8, h = idx & 255;
    float w = W1[idx];
    sa = fmaf(gamma[d], w, sa);
    ta = fmaf(beta[d], w, ta);
    bf16 hi = (bf16)w;  float r1 = w - (float)hi;
    bf16 mi = (bf16)r1; float r2 = r1 - (float)mi;
    bf16 lo = (bf16)r2;
    int ks = d >> 5, kg = (d >> 3) & 3, kk = d & 7;
    int nf = h >> 4, nn = h & 15;
    size_t base = (((size_t)ks * 3 * 16 + nf) * 4 + kg) * 128 + nn * 8 + kk;
    const size_t spStride = 16 * 4 * 128;  // 8192 elems per split per K-step
    W1F[base] = hi;
    W1F[base + spStride] = mi;
    W1F[base + 2 * spStride] = lo;
  }
  ps[t] = sa; pt[t] = ta;
  __syncthreads();
  if (t < 256) {
    Spart[b * 256 + t] = ps[t] + ps[t + 256] + ps[t + 512] + ps[t + 768];
    Tpart[b * 256 + t] = pt[t] + pt[t + 256] + pt[t + 512] + pt[t + 768];
  }
}

__global__ __launch_bounds__(256) void prep_combine(
    const float* __restrict__ Spart, const float* __restrict__ Tpart,
    const float* __restrict__ b1, float* __restrict__ S, float* __restrict__ Tb) {
  int j = threadIdx.x;
  float s = 0.f, t = 0.f;
  for (int b = 0; b < 32; ++b) { s += Spart[b * 256 + j]; t += Tpart[b * 256 + j]; }
  S[j] = s;
  Tb[j] = t + b1[j];
}

// ---------------- scores: fused LN + Linear(1024->256) + GELU + Linear(256->1)
// 3-way-split bf16 MFMA (6 products), T3-lite pipeline: LDS double-buffer,
// ONE barrier per K-step, A raw tile reg-prefetched 2 ahead (split VALU
// overlaps MFMA on separate pipes), B staged via async global_load_lds from
// the L2-resident pre-formatted W1F. FP order identical to round 5.
__global__ __launch_bounds__(1024) void scores_mfma(
    const float* __restrict__ F, const float* __restrict__ gamma,
    const bf16* __restrict__ W1F,
    const float* __restrict__ S, const float* __restrict__ Tb,
    const float* __restrict__ W2, const float* __restrict__ b2,
    float* __restrict__ scores_out) {
  __shared__ bf16 As[2][12288];    // 2 x 24KB  [sp(3)][kg(4)][row(128)][k8]
  __shared__ bf16 Bs[2][24576];    // 2 x 48KB  [sp(3)][nf(16)][kg(4)][n16*k8]
  __shared__ float smu[128], srs[128];
  __shared__ float sred[128][8];

  const int tid = threadIdx.x;
  const int RM = blockIdx.x * 128;
  const int wid = tid >> 6, lane = tid & 63;
  const int wm = wid & 1, wn = wid >> 1;     // wn 0..7 (32-col slice)
  const int lg = lane >> 4, l15 = lane & 15;

  // A staging: thread -> (row, k-quarter of 4 elems)
  const int arow = tid >> 3, akq = tid & 7;
  const int kg = akq >> 1, joff = (akq & 1) * 4;
  const int abase = kg * 1024 + arow * 8 + joff;
  const float* Aptr = F + (size_t)(RM + arow) * Dk + akq * 4;

  f32x4 acc[4][2];
  #pragma unroll
  for (int i = 0; i < 4; ++i)
    #pragma unroll
    for (int j = 0; j < 2; ++j) acc[i][j] = (f32x4){0.f, 0.f, 0.f, 0.f};

  float rsum = 0.f, rsq = 0.f;

  // split av*gv -> 3 bf16x4 rows of As[buf] + stats (fp32 order = round 5)
#define SPLIT_STORE(buf, av, gv)                                               \
  {                                                                            \
    rsum += av.x + av.y + av.z + av.w;                                         \
    rsq = fmaf(av.x, av.x, fmaf(av.y, av.y,                                    \
              fmaf(av.z, av.z, fmaf(av.w, av.w, rsq))));                       \
    float x0 = av.x * gv.x, x1 = av.y * gv.y, x2 = av.z * gv.z,                \
          x3 = av.w * gv.w;                                                    \
    bf16 h0 = (bf16)x0, h1 = (bf16)x1, h2 = (bf16)x2, h3 = (bf16)x3;           \
    float r0 = x0 - (float)h0, r1 = x1 - (float)h1, r2 = x2 - (float)h2,       \
          r3 = x3 - (float)h3;                                                 \
    bf16 m0 = (bf16)r0, m1 = (bf16)r1, m2 = (bf16)r2, m3 = (bf16)r3;           \
    bf16 l0 = (bf16)(r0 - (float)m0), l1 = (bf16)(r1 - (float)m1);             \
    bf16 l2 = (bf16)(r2 - (float)m2), l3 = (bf16)(r3 - (float)m3);             \
    *reinterpret_cast<bf16x4*>(&As[buf][abase])        = (bf16x4){h0,h1,h2,h3};\
    *reinterpret_cast<bf16x4*>(&As[buf][abase + 4096]) = (bf16x4){m0,m1,m2,m3};\
    *reinterpret_cast<bf16x4*>(&As[buf][abase + 8192]) = (bf16x4){l0,l1,l2,l3};\
  }

  // ---- prologue: stage step 0 into buf 0, prefetch A raw for step 1
  float4 av = *reinterpret_cast<const float4*>(Aptr);
  float4 gv = *reinterpret_cast<const float4*>(gamma + akq * 4);
  SPLIT_STORE(0, av, gv);
  #pragma unroll
  for (int c = 0; c < 3; ++c) {
    int cid = tid + c * 1024;
    GLD_LDS16(W1F + (size_t)cid * 8, &Bs[0][cid * 8]);
  }
  av = *reinterpret_cast<const float4*>(Aptr + 32);
  gv = *reinterpret_cast<const float4*>(gamma + 32 + akq * 4);
  __syncthreads();   // drains vmcnt (B tile 0) + lgkmcnt (A writes)

  for (int s = 0; s < 32; ++s) {
    const int cur = s & 1;
    // B fragments for this step
    bf16x8 bfr[2][3];
    #pragma unroll
    for (int nf = 0; nf < 2; ++nf)
      #pragma unroll
      for (int sp = 0; sp < 3; ++sp)
        bfr[nf][sp] = *reinterpret_cast<const bf16x8*>(
            &Bs[cur][((sp * 16 + (wn * 2 + nf)) * 4 + lg) * 128 + l15 * 8]);
    // stage step s+1 into the other buffer (overlaps with MFMA below)
    if (s < 31) {
      const bf16* Bsrc = W1F + (size_t)(s + 1) * 24576;
      #pragma unroll
      for (int c = 0; c < 3; ++c) {
        int cid = tid + c * 1024;
        GLD_LDS16(Bsrc + (size_t)cid * 8, &Bs[cur ^ 1][cid * 8]);
      }
      SPLIT_STORE(cur ^ 1, av, gv);
      if (s < 30) {
        av = *reinterpret_cast<const float4*>(Aptr + (s + 2) * 32);
        gv = *reinterpret_cast<const float4*>(gamma + (s + 2) * 32 + akq * 4);
      }
    }
    // MFMA: wave tile 64x32 = 4 mfrag x 2 nfrag, 6 split-products each
    #pragma unroll
    for (int mf = 0; mf < 4; ++mf) {
      bf16x8 afr[3];
      #pragma unroll
      for (int sp = 0; sp < 3; ++sp)
        afr[sp] = *reinterpret_cast<const bf16x8*>(
            &As[cur][(sp * 4 + lg) * 1024 + (wm * 64 + mf * 16 + l15) * 8]);
      #pragma unroll
      for (int nf = 0; nf < 2; ++nf) {
        f32x4 a = acc[mf][nf];
        a = __builtin_amdgcn_mfma_f32_16x16x32_bf16(afr[0], bfr[nf][0], a, 0, 0, 0);
        a = __builtin_amdgcn_mfma_f32_16x16x32_bf16(afr[0], bfr[nf][1], a, 0, 0, 0);
        a = __builtin_amdgcn_mfma_f32_16x16x32_bf16(afr[1], bfr[nf][0], a, 0, 0, 0);
        a = __builtin_amdgcn_mfma_f32_16x16x32_bf16(afr[1], bfr[nf][1], a, 0, 0, 0);
        a = __builtin_amdgcn_mfma_f32_16x16x32_bf16(afr[0], bfr[nf][2], a, 0, 0, 0);
        a = __builtin_amdgcn_mfma_f32_16x16x32_bf16(afr[2], bfr[nf][0], a, 0, 0, 0);
        acc[mf][nf] = a;
      }
    }
    __syncthreads();  // one barrier/step: drains gld_lds(s+1) + A writes(s+1)
  }

  // finish stats: row owned by 8 lanes (tid&7)
  rsum += __shfl_xor(rsum, 1); rsum += __shfl_xor(rsum, 2); rsum += __shfl_xor(rsum, 4);
  rsq  += __shfl_xor(rsq, 1);  rsq  += __shfl_xor(rsq, 2);  rsq  += __shfl_xor(rsq, 4);
  if ((tid & 7) == 0) {
    float mu  = rsum * (1.f / 1024.f);
    float var = rsq * (1.f / 1024.f) - mu * mu;
    smu[arow] = mu;
    srs[arow] = rsqrtf(var + 1e-5f);
  }
  __syncthreads();

  // epilogue: C/D layout col=l15, row=lg*4+reg. LN affine + GELU(exact) +
  // W2 dot; 16-lane reduce; cross-wave via sred (fixed order => deterministic).
  float s2[2], tb2[2], w2v[2];
  #pragma unroll
  for (int nf = 0; nf < 2; ++nf) {
    int col = wn * 32 + nf * 16 + l15;
    s2[nf] = S[col]; tb2[nf] = Tb[col]; w2v[nf] = W2[col];
  }
  #pragma unroll
  for (int mf = 0; mf < 4; ++mf) {
    const int rbase = wm * 64 + mf * 16 + lg * 4;
    #pragma unroll
    for (int reg = 0; reg < 4; ++reg) {
      const int row = rbase + reg;
      float mu = smu[row], rs = srs[row];
      float part = 0.f;
      #pragma unroll
      for (int nf = 0; nf < 2; ++nf) {
        float hpre = rs * acc[mf][nf][reg] - rs * mu * s2[nf] + tb2[nf];
        float g = 0.5f * hpre * (1.f + erff(hpre * 0.70710678118654752f));
        part = fmaf(g, w2v[nf], part);
      }
      part += __shfl_xor(part, 1); part += __shfl_xor(part, 2);
      part += __shfl_xor(part, 4); part += __shfl_xor(part, 8);
      if (l15 == 0) sred[row][wn] = part;
    }
  }
  __syncthreads();
  if (tid < 128) {
    float sc = b2[0];
    #pragma unroll
    for (int w = 0; w < 8; ++w) sc += sred[tid][w];
    scores_out[RM + tid] = sc;
  }
}

// ---------------- topk: per-batch full bitonic sort of (descending score, ascending idx)
__global__ __launch_bounds__(1024) void topk_kernel(
    const float* __restrict__ scores, int k,
    float* __restrict__ idx_f, int* __restrict__ idx_i) {
  __shared__ unsigned long long keys[Lk];  // 64 KB
  const int b = blockIdx.x, t = threadIdx.x;
  for (int i = t; i < Lk; i += 1024) {
    unsigned u = __float_as_uint(scores[(size_t)b * Lk + i]);
    unsigned mono = (u & 0x80000000u) ? ~u : (u | 0x80000000u);  // ascending in value
    keys[i] = ((unsigned long long)(~mono) << 32) | (unsigned)i; // asc sort => desc score, asc idx
  }
  __syncthreads();
  for (int size = 2; size <= Lk; size <<= 1) {
    for (int stride = size >> 1; stride > 0; stride >>= 1) {
      for (int p = t; p < Lk / 2; p += 1024) {
        int lo = ((p & ~(stride - 1)) << 1) | (p & (stride - 1));
        int hi = lo + stride;
        bool up = ((lo & size) == 0);
        unsigned long long a = keys[lo], c = keys[hi];
        if ((a > c) == up) { keys[lo] = c; keys[hi] = a; }
      }
      __syncthreads();
    }
  }
  for (int i = t; i < k; i += 1024) {
    int id = (int)(keys[i] & 0xFFFFFFFFu);
    idx_f[(size_t)b * k + i] = (float)id;  // out buffer is fp32; indices exact in fp32
    idx_i[(size_t)b * k + i] = id;
  }
}

// ---------------- gather: one block per selected row, 4 KB float4 copy
__global__ __launch_bounds__(256) void gather_kernel(
    const float* __restrict__ F, const int* __restrict__ idx,
    float* __restrict__ out, int k) {
  int row = blockIdx.x;          // 0 .. 8*k-1
  int b = row / k;
  int id = idx[row];
  const float4* src = reinterpret_cast<const float4*>(F + ((size_t)b * Lk + id) * Dk);
  float4* dst = reinterpret_cast<float4*>(out + (size_t)row * Dk);
  dst[threadIdx.x] = src[threadIdx.x];
}

extern "C" void kernel_launch(void* const* d_in, const int* in_sizes, int n_in,
                              void* d_out, int out_size, void* d_ws, size_t ws_size,
                              hipStream_t stream) {
  const float* F     = (const float*)d_in[0];
  const float* gamma = (const float*)d_in[1];
  const float* beta  = (const float*)d_in[2];
  const float* W1    = (const float*)d_in[3];
  const float* b1    = (const float*)d_in[4];
  const float* W2    = (const float*)d_in[5];
  const float* b2    = (const float*)d_in[6];
  // k lives on device; derive on host from out_size = 8*k*1024 + 8*8192 + 8*k
  int k = (out_size - Bk * Lk) / (Bk * Dk + Bk);   // = 512

  float* out_sel = (float*)d_out;                       // [8, k, 1024]
  float* out_sc  = out_sel + (size_t)Bk * k * Dk;       // [8, 8192]
  float* out_idx = out_sc + (size_t)Bk * Lk;            // [8, k] as float

  // ws: W1F bf16[786432] (1.5MB) | Spart f32[8192] | Tpart f32[8192] |
  //     S f32[256] | Tb f32[256] | idxi i32[8*k]
  bf16*  W1F   = (bf16*)d_ws;
  float* Spart = (float*)((char*)d_ws + 786432 * sizeof(bf16));
  float* Tpart = Spart + 8192;
  float* Sp    = Tpart + 8192;
  float* Tbp   = Sp + Hk;
  int*   idxi  = (int*)(Tbp + Hk);

  hipLaunchKernelGGL(prep_split,   dim3(32),         dim3(1024), 0, stream,
                     W1, gamma, beta, W1F, Spart, Tpart);
  hipLaunchKernelGGL(prep_combine, dim3(1),          dim3(Hk),   0, stream,
                     Spart, Tpart, b1, Sp, Tbp);
  hipLaunchKernelGGL(scores_mfma,  dim3(MTOT / 128), dim3(1024), 0, stream,
                     F, gamma, W1F, Sp, Tbp, W2, b2, out_sc);
  hipLaunchKernelGGL(topk_kernel,  dim3(Bk),         dim3(1024), 0, stream,
                     out_sc, k, out_idx, idxi);
  hipLaunchKernelGGL(gather_kernel, dim3(Bk * k),    dim3(256),  0, stream,
                     F, idxi, out_sel, k);
}

// Round 7
// 230.082 us; speedup vs baseline: 42.1975x; 1.1521x over previous
//
#include <hip/hip_runtime.h>
#include <math.h>

#define Dk 1024
#define Hk 256
#define Lk 8192
#define Bk 8
#define MTOT (Bk*Lk)   // 65536 rows

typedef _Float16 f16;
typedef __attribute__((ext_vector_type(8))) _Float16 f16x8;
typedef __attribute__((ext_vector_type(4))) float f32x4;

#define AKG 1048            // padded k8-group stride (elems): 2096B -> kg bank offsets all distinct
#define ASP (8*AKG)         // split stride (8 kgs per BK=64 step)
#define ABUF (2*ASP)        // elems per LDS buffer (2 splits)

// ---------------- prep_split: W1 -> gamma-folded fp16 2-way split (hi, lo*2048)
// in MFMA-fragment order, PLUS partials for S = gamma@W1, T = beta@W1.
// Layout: W1F[ks(16)][sp(2)][nf(16)][kg(8)][n(16)][k(8)], d=ks*64+kg*8+k, h=nf*16+n.
__global__ __launch_bounds__(1024) void prep_split(
    const float* __restrict__ W1, const float* __restrict__ gamma,
    const float* __restrict__ beta, f16* __restrict__ W1F,
    float* __restrict__ Spart, float* __restrict__ Tpart) {
  __shared__ float ps[1024], pt[1024];
  const int b = blockIdx.x, t = threadIdx.x;
  float sa = 0.f, ta = 0.f;
  #pragma unroll
  for (int j = 0; j < 4; ++j) {
    int idx = j * 65536 + b * 1024 + t;
    int d = idx >> 8, h = idx & 255;
    float w = W1[idx];
    float g = gamma[d];
    sa = fmaf(g, w, sa);
    ta = fmaf(beta[d], w, ta);
    float wg = g * w;                       // gamma folded into W1
    f16 whi = (f16)wg;
    f16 wlp = (f16)((wg - (float)whi) * 2048.f);   // scaled lo: stays fp16-normal
    int ks = d >> 6, kg = (d >> 3) & 7, kk = d & 7;
    int nf = h >> 4, nn = h & 15;
    size_t base = ((((size_t)ks * 2) * 16 + nf) * 8 + kg) * 128 + nn * 8 + kk;
    W1F[base] = whi;
    W1F[base + 16384] = wlp;                // sp stride = 16*8*128
  }
  ps[t] = sa; pt[t] = ta;
  __syncthreads();
  if (t < 256) {
    Spart[b * 256 + t] = ps[t] + ps[t + 256] + ps[t + 512] + ps[t + 768];
    Tpart[b * 256 + t] = pt[t] + pt[t + 256] + pt[t + 512] + pt[t + 768];
  }
}

__global__ __launch_bounds__(256) void prep_combine(
    const float* __restrict__ Spart, const float* __restrict__ Tpart,
    const float* __restrict__ b1, float* __restrict__ S, float* __restrict__ Tb) {
  int j = threadIdx.x;
  float s = 0.f, t = 0.f;
  for (int b = 0; b < 64; ++b) { s += Spart[b * 256 + j]; t += Tpart[b * 256 + j]; }
  S[j] = s;
  Tb[j] = t + b1[j];
}

// ---------------- scores: fused LN + Linear(1024->256) + GELU + Linear(256->1)
// fp16 2-way-split MFMA, 4 products into dual accumulators:
//   accA += hi*whi ;  accB += hi*wl' + xl'*whi + xl'*(wl'*2^-11)
//   value = accA + accB/2048      (error ~2e-7 rel, safe vs ~6e-4 rank spacing)
// BK=64, 16 K-steps, one barrier/step, LDS dbuf A only; B fragments straight
// from L2-resident W1F. 16 waves (2M x 8N), wave tile 64x32.
__global__ __launch_bounds__(1024) void scores_mfma(
    const float* __restrict__ F, const f16* __restrict__ W1F,
    const float* __restrict__ S, const float* __restrict__ Tb,
    const float* __restrict__ W2, const float* __restrict__ b2,
    float* __restrict__ scores_out) {
  __shared__ f16 As[2][ABUF];      // 2 x 33.5KB: [sp(2)][kg(8)][row(128)][k8]
  __shared__ float smu[128], srs[128];
  __shared__ float sred[128][8];

  const int tid = threadIdx.x;
  const int RM = blockIdx.x * 128;
  const int wid = tid >> 6, lane = tid & 63;
  const int wm = wid & 1, wn = wid >> 1;     // wn 0..7: 32-col slice
  const int lg = lane >> 4, l15 = lane & 15;

  // A staging: thread -> (row, one k8-group of the 64-wide K step)
  const int arow = tid >> 3, kg = tid & 7;
  const float* Aptr = F + (size_t)(RM + arow) * Dk + kg * 8;

  f32x4 accA[4][2], accB[4][2];
  #pragma unroll
  for (int i = 0; i < 4; ++i)
    #pragma unroll
    for (int j = 0; j < 2; ++j) {
      accA[i][j] = (f32x4){0.f, 0.f, 0.f, 0.f};
      accB[i][j] = (f32x4){0.f, 0.f, 0.f, 0.f};
    }

  float rsum = 0.f, rsq = 0.f;

  // stats + fp16 2-way split of 8 raw elems -> two b128 LDS writes
#define SPLIT_STORE(buf, av0, av1)                                             \
  {                                                                            \
    float xx[8] = {av0.x, av0.y, av0.z, av0.w, av1.x, av1.y, av1.z, av1.w};    \
    f16x8 vhi, vlo;                                                            \
    _Pragma("unroll")                                                          \
    for (int e = 0; e < 8; ++e) {                                              \
      float x = xx[e];                                                         \
      rsum += x; rsq = fmaf(x, x, rsq);                                        \
      f16 hi = (f16)x;                                                         \
      vhi[e] = hi;                                                             \
      vlo[e] = (f16)((x - (float)hi) * 2048.f);                                \
    }                                                                          \
    *reinterpret_cast<f16x8*>(&As[buf][kg * AKG + arow * 8]) = vhi;            \
    *reinterpret_cast<f16x8*>(&As[buf][ASP + kg * AKG + arow * 8]) = vlo;      \
  }

  // prologue: stage tile 0, prefetch raw tile 1
  float4 av0 = *reinterpret_cast<const float4*>(Aptr);
  float4 av1 = *reinterpret_cast<const float4*>(Aptr + 4);
  SPLIT_STORE(0, av0, av1)
  av0 = *reinterpret_cast<const float4*>(Aptr + 64);
  av1 = *reinterpret_cast<const float4*>(Aptr + 68);
  __syncthreads();

  for (int s = 0; s < 16; ++s) {
    const int cur = s & 1;
    // lane base into this step's fragment block (nf=0, sp=0, kw=0)
    const f16* bbase = W1F + (size_t)s * 32768
                     + ((size_t)(wn * 2) * 8 + lg) * 128 + l15 * 8;
    #pragma unroll
    for (int kw = 0; kw < 2; ++kw) {
      // B fragments from global (L2): frag += nf*1024, sp*16384, kw*512
      f16x8 whi0 = *reinterpret_cast<const f16x8*>(bbase + kw * 512);
      f16x8 whi1 = *reinterpret_cast<const f16x8*>(bbase + kw * 512 + 1024);
      f16x8 wlp0 = *reinterpret_cast<const f16x8*>(bbase + kw * 512 + 16384);
      f16x8 wlp1 = *reinterpret_cast<const f16x8*>(bbase + kw * 512 + 17408);
      f16x8 wlr0 = wlp0 * (f16)0.00048828125f;   // exact *2^-11 (v_pk_mul_f16)
      f16x8 wlr1 = wlp1 * (f16)0.00048828125f;
      #pragma unroll
      for (int mf = 0; mf < 4; ++mf) {
        const int abase = (kw * 4 + lg) * AKG + (wm * 64 + mf * 16 + l15) * 8;
        f16x8 ahi = *reinterpret_cast<const f16x8*>(&As[cur][abase]);
        f16x8 axl = *reinterpret_cast<const f16x8*>(&As[cur][ASP + abase]);
        accA[mf][0] = __builtin_amdgcn_mfma_f32_16x16x32_f16(ahi, whi0, accA[mf][0], 0, 0, 0);
        accB[mf][0] = __builtin_amdgcn_mfma_f32_16x16x32_f16(ahi, wlp0, accB[mf][0], 0, 0, 0);
        accB[mf][0] = __builtin_amdgcn_mfma_f32_16x16x32_f16(axl, whi0, accB[mf][0], 0, 0, 0);
        accB[mf][0] = __builtin_amdgcn_mfma_f32_16x16x32_f16(axl, wlr0, accB[mf][0], 0, 0, 0);
        accA[mf][1] = __builtin_amdgcn_mfma_f32_16x16x32_f16(ahi, whi1, accA[mf][1], 0, 0, 0);
        accB[mf][1] = __builtin_amdgcn_mfma_f32_16x16x32_f16(ahi, wlp1, accB[mf][1], 0, 0, 0);
        accB[mf][1] = __builtin_amdgcn_mfma_f32_16x16x32_f16(axl, whi1, accB[mf][1], 0, 0, 0);
        accB[mf][1] = __builtin_amdgcn_mfma_f32_16x16x32_f16(axl, wlr1, accB[mf][1], 0, 0, 0);
      }
    }
    if (s < 15) {
      SPLIT_STORE(cur ^ 1, av0, av1)   // tile s+1 (stats order sequential)
      if (s < 14) {
        av0 = *reinterpret_cast<const float4*>(Aptr + (s + 2) * 64);
        av1 = *reinterpret_cast<const float4*>(Aptr + (s + 2) * 64 + 4);
      }
    }
    __syncthreads();  // one barrier/step: A writes for s+1 visible, reads done
  }

  // finish stats: row owned by 8 threads (kg 0..7)
  rsum += __shfl_xor(rsum, 1); rsum += __shfl_xor(rsum, 2); rsum += __shfl_xor(rsum, 4);
  rsq  += __shfl_xor(rsq, 1);  rsq  += __shfl_xor(rsq, 2);  rsq  += __shfl_xor(rsq, 4);
  if ((tid & 7) == 0) {
    float mu  = rsum * (1.f / 1024.f);
    float var = rsq * (1.f / 1024.f) - mu * mu;
    smu[arow] = mu;
    srs[arow] = rsqrtf(var + 1e-5f);
  }
  __syncthreads();

  // epilogue: C/D col=l15, row=lg*4+reg. val = accA + accB/2048; LN affine +
  // GELU(exact) + W2 dot; 16-lane reduce; cross-wave via sred (fixed order).
  float s2[2], tb2[2], w2v[2];
  #pragma unroll
  for (int nf = 0; nf < 2; ++nf) {
    int col = wn * 32 + nf * 16 + l15;
    s2[nf] = S[col]; tb2[nf] = Tb[col]; w2v[nf] = W2[col];
  }
  #pragma unroll
  for (int mf = 0; mf < 4; ++mf) {
    const int rbase = wm * 64 + mf * 16 + lg * 4;
    #pragma unroll
    for (int reg = 0; reg < 4; ++reg) {
      const int row = rbase + reg;
      float mu = smu[row], rs = srs[row];
      float part = 0.f;
      #pragma unroll
      for (int nf = 0; nf < 2; ++nf) {
        float val = accA[mf][nf][reg] + accB[mf][nf][reg] * (1.f / 2048.f);
        float hpre = rs * val - rs * mu * s2[nf] + tb2[nf];
        float g = 0.5f * hpre * (1.f + erff(hpre * 0.70710678118654752f));
        part = fmaf(g, w2v[nf], part);
      }
      part += __shfl_xor(part, 1); part += __shfl_xor(part, 2);
      part += __shfl_xor(part, 4); part += __shfl_xor(part, 8);
      if (l15 == 0) sred[row][wn] = part;
    }
  }
  __syncthreads();
  if (tid < 128) {
    float sc = b2[0];
    #pragma unroll
    for (int w = 0; w < 8; ++w) sc += sred[tid][w];
    scores_out[RM + tid] = sc;
  }
}

// ---------------- topk: per-batch full bitonic sort of (descending score, ascending idx)
__global__ __launch_bounds__(1024) void topk_kernel(
    const float* __restrict__ scores, int k,
    float* __restrict__ idx_f, int* __restrict__ idx_i) {
  __shared__ unsigned long long keys[Lk];  // 64 KB
  const int b = blockIdx.x, t = threadIdx.x;
  for (int i = t; i < Lk; i += 1024) {
    unsigned u = __float_as_uint(scores[(size_t)b * Lk + i]);
    unsigned mono = (u & 0x80000000u) ? ~u : (u | 0x80000000u);  // ascending in value
    keys[i] = ((unsigned long long)(~mono) << 32) | (unsigned)i; // asc sort => desc score, asc idx
  }
  __syncthreads();
  for (int size = 2; size <= Lk; size <<= 1) {
    for (int stride = size >> 1; stride > 0; stride >>= 1) {
      for (int p = t; p < Lk / 2; p += 1024) {
        int lo = ((p & ~(stride - 1)) << 1) | (p & (stride - 1));
        int hi = lo + stride;
        bool up = ((lo & size) == 0);
        unsigned long long a = keys[lo], c = keys[hi];
        if ((a > c) == up) { keys[lo] = c; keys[hi] = a; }
      }
      __syncthreads();
    }
  }
  for (int i = t; i < k; i += 1024) {
    int id = (int)(keys[i] & 0xFFFFFFFFu);
    idx_f[(size_t)b * k + i] = (float)id;  // out buffer is fp32; indices exact in fp32
    idx_i[(size_t)b * k + i] = id;
  }
}

// ---------------- gather: one block per selected row, 4 KB float4 copy
__global__ __launch_bounds__(256) void gather_kernel(
    const float* __restrict__ F, const int* __restrict__ idx,
    float* __restrict__ out, int k) {
  int row = blockIdx.x;          // 0 .. 8*k-1
  int b = row / k;
  int id = idx[row];
  const float4* src = reinterpret_cast<const float4*>(F + ((size_t)b * Lk + id) * Dk);
  float4* dst = reinterpret_cast<float4*>(out + (size_t)row * Dk);
  dst[threadIdx.x] = src[threadIdx.x];
}

extern "C" void kernel_launch(void* const* d_in, const int* in_sizes, int n_in,
                              void* d_out, int out_size, void* d_ws, size_t ws_size,
                              hipStream_t stream) {
  const float* F     = (const float*)d_in[0];
  const float* gamma = (const float*)d_in[1];
  const float* beta  = (const float*)d_in[2];
  const float* W1    = (const float*)d_in[3];
  const float* b1    = (const float*)d_in[4];
  const float* W2    = (const float*)d_in[5];
  const float* b2    = (const float*)d_in[6];
  // k lives on device; derive on host from out_size = 8*k*1024 + 8*8192 + 8*k
  int k = (out_size - Bk * Lk) / (Bk * Dk + Bk);   // = 512

  float* out_sel = (float*)d_out;                       // [8, k, 1024]
  float* out_sc  = out_sel + (size_t)Bk * k * Dk;       // [8, 8192]
  float* out_idx = out_sc + (size_t)Bk * Lk;            // [8, k] as float

  // ws: W1F f16[524288] (1MB) | Spart f32[16384] | Tpart f32[16384] |
  //     S f32[256] | Tb f32[256] | idxi i32[8*k]
  f16*   W1F   = (f16*)d_ws;
  float* Spart = (float*)((char*)d_ws + 524288 * sizeof(f16));
  float* Tpart = Spart + 16384;
  float* Sp    = Tpart + 16384;
  float* Tbp   = Sp + Hk;
  int*   idxi  = (int*)(Tbp + Hk);

  hipLaunchKernelGGL(prep_split,   dim3(64),         dim3(1024), 0, stream,
                     W1, gamma, beta, W1F, Spart, Tpart);
  hipLaunchKernelGGL(prep_combine, dim3(1),          dim3(Hk),   0, stream,
                     Spart, Tpart, b1, Sp, Tbp);
  hipLaunchKernelGGL(scores_mfma,  dim3(MTOT / 128), dim3(1024), 0, stream,
                     F, W1F, Sp, Tbp, W2, b2, out_sc);
  hipLaunchKernelGGL(topk_kernel,  dim3(Bk),         dim3(1024), 0, stream,
                     out_sc, k, out_idx, idxi);
  hipLaunchKernelGGL(gather_kernel, dim3(Bk * k),    dim3(256),  0, stream,
                     F, idxi, out_sel, k);
}

// Round 8
// 217.896 us; speedup vs baseline: 44.5575x; 1.0559x over previous
//
#include <hip/hip_runtime.h>
#include <math.h>

#define Dk 1024
#define Hk 256
#define Lk 8192
#define Bk 8
#define MTOT (Bk*Lk)   // 65536 rows

typedef _Float16 f16;
typedef __attribute__((ext_vector_type(8))) _Float16 f16x8;
typedef __attribute__((ext_vector_type(4))) float f32x4;

#define AKG 1048            // padded k8-group stride (elems)
#define ASP (8*AKG)         // split stride (8 kgs per BK=64 step)
#define ABUF (2*ASP)        // elems per LDS buffer (2 splits)

// ---------------- prep_split: W1 -> gamma-folded fp16 2-way split (hi, lo*2048)
// in MFMA-fragment order, PLUS partials for S = gamma@W1, T = beta@W1.
// Layout: W1F[ks(16)][sp(2)][nf(16)][kg(8)][n(16)][k(8)], d=ks*64+kg*8+k, h=nf*16+n.
__global__ __launch_bounds__(1024) void prep_split(
    const float* __restrict__ W1, const float* __restrict__ gamma,
    const float* __restrict__ beta, f16* __restrict__ W1F,
    float* __restrict__ Spart, float* __restrict__ Tpart) {
  __shared__ float ps[1024], pt[1024];
  const int b = blockIdx.x, t = threadIdx.x;
  float sa = 0.f, ta = 0.f;
  #pragma unroll
  for (int j = 0; j < 4; ++j) {
    int idx = j * 65536 + b * 1024 + t;
    int d = idx >> 8, h = idx & 255;
    float w = W1[idx];
    float g = gamma[d];
    sa = fmaf(g, w, sa);
    ta = fmaf(beta[d], w, ta);
    float wg = g * w;                       // gamma folded into W1
    f16 whi = (f16)wg;
    f16 wlp = (f16)((wg - (float)whi) * 2048.f);   // scaled lo: stays fp16-normal
    int ks = d >> 6, kg = (d >> 3) & 7, kk = d & 7;
    int nf = h >> 4, nn = h & 15;
    size_t base = ((((size_t)ks * 2) * 16 + nf) * 8 + kg) * 128 + nn * 8 + kk;
    W1F[base] = whi;
    W1F[base + 16384] = wlp;                // sp stride = 16*8*128
  }
  ps[t] = sa; pt[t] = ta;
  __syncthreads();
  if (t < 256) {
    Spart[b * 256 + t] = ps[t] + ps[t + 256] + ps[t + 512] + ps[t + 768];
    Tpart[b * 256 + t] = pt[t] + pt[t + 256] + pt[t + 512] + pt[t + 768];
  }
}

__global__ __launch_bounds__(256) void prep_combine(
    const float* __restrict__ Spart, const float* __restrict__ Tpart,
    const float* __restrict__ b1, float* __restrict__ S, float* __restrict__ Tb) {
  int j = threadIdx.x;
  float s = 0.f, t = 0.f;
  for (int b = 0; b < 64; ++b) { s += Spart[b * 256 + j]; t += Tpart[b * 256 + j]; }
  S[j] = s;
  Tb[j] = t + b1[j];
}

// ---------------- scores: fused LN + Linear(1024->256) + GELU + Linear(256->1)
// fp16 2-way-split MFMA, 4 products into dual accumulators:
//   accA += hi*whi ;  accB += hi*wl' + xl'*whi + xl'*(wl'*2^-11)
//   value = accA + accB/2048
// Step order (round-8 reorder): issue kw0 B-loads -> SPLIT_STORE(s+1) VALU
// hides the L2 latency -> kw0 MFMAs -> kw1 loads+MFMAs (hidden under kw0
// MFMAs) -> A raw prefetch -> barrier. FP order identical to round 7.
__global__ __launch_bounds__(1024) void scores_mfma(
    const float* __restrict__ F, const f16* __restrict__ W1F,
    const float* __restrict__ S, const float* __restrict__ Tb,
    const float* __restrict__ W2, const float* __restrict__ b2,
    float* __restrict__ scores_out) {
  __shared__ f16 As[2][ABUF];      // 2 x 33.5KB: [sp(2)][kg(8)][row(128)][k8]
  __shared__ float smu[128], srs[128];
  __shared__ float sred[128][8];

  const int tid = threadIdx.x;
  const int RM = blockIdx.x * 128;
  const int wid = tid >> 6, lane = tid & 63;
  const int wm = wid & 1, wn = wid >> 1;     // wn 0..7: 32-col slice
  const int lg = lane >> 4, l15 = lane & 15;

  // A staging: thread -> (row, one k8-group of the 64-wide K step)
  const int arow = tid >> 3, kg = tid & 7;
  const float* Aptr = F + (size_t)(RM + arow) * Dk + kg * 8;

  f32x4 accA[4][2], accB[4][2];
  #pragma unroll
  for (int i = 0; i < 4; ++i)
    #pragma unroll
    for (int j = 0; j < 2; ++j) {
      accA[i][j] = (f32x4){0.f, 0.f, 0.f, 0.f};
      accB[i][j] = (f32x4){0.f, 0.f, 0.f, 0.f};
    }

  float rsum = 0.f, rsq = 0.f;

  // stats + fp16 2-way split of 8 raw elems -> two b128 LDS writes
#define SPLIT_STORE(buf, av0, av1)                                             \
  {                                                                            \
    float xx[8] = {av0.x, av0.y, av0.z, av0.w, av1.x, av1.y, av1.z, av1.w};    \
    f16x8 vhi, vlo;                                                            \
    _Pragma("unroll")                                                          \
    for (int e = 0; e < 8; ++e) {                                              \
      float x = xx[e];                                                         \
      rsum += x; rsq = fmaf(x, x, rsq);                                        \
      f16 hi = (f16)x;                                                         \
      vhi[e] = hi;                                                             \
      vlo[e] = (f16)((x - (float)hi) * 2048.f);                                \
    }                                                                          \
    *reinterpret_cast<f16x8*>(&As[buf][kg * AKG + arow * 8]) = vhi;            \
    *reinterpret_cast<f16x8*>(&As[buf][ASP + kg * AKG + arow * 8]) = vlo;      \
  }

  // prologue: stage tile 0, prefetch raw tile 1
  float4 av0 = *reinterpret_cast<const float4*>(Aptr);
  float4 av1 = *reinterpret_cast<const float4*>(Aptr + 4);
  SPLIT_STORE(0, av0, av1)
  av0 = *reinterpret_cast<const float4*>(Aptr + 64);
  av1 = *reinterpret_cast<const float4*>(Aptr + 68);
  __syncthreads();

  for (int s = 0; s < 16; ++s) {
    const int cur = s & 1;
    // lane base into this step's fragment block (nf=0, sp=0, kw=0)
    const f16* bbase = W1F + (size_t)s * 32768
                     + ((size_t)(wn * 2) * 8 + lg) * 128 + l15 * 8;
    // ---- issue kw0 B loads FIRST (L2 latency hidden by the split below)
    f16x8 whi0_0 = *reinterpret_cast<const f16x8*>(bbase);
    f16x8 whi1_0 = *reinterpret_cast<const f16x8*>(bbase + 1024);
    f16x8 wlp0_0 = *reinterpret_cast<const f16x8*>(bbase + 16384);
    f16x8 wlp1_0 = *reinterpret_cast<const f16x8*>(bbase + 17408);
    // ---- split tile s+1 (pure VALU + LDS writes, overlaps B-load latency)
    if (s < 15) {
      SPLIT_STORE(cur ^ 1, av0, av1)
      if (s < 14) {
        av0 = *reinterpret_cast<const float4*>(Aptr + (s + 2) * 64);
        av1 = *reinterpret_cast<const float4*>(Aptr + (s + 2) * 64 + 4);
      }
    }
    // ---- kw0 MFMAs
    {
      f16x8 wlr0 = wlp0_0 * (f16)0.00048828125f;   // exact *2^-11
      f16x8 wlr1 = wlp1_0 * (f16)0.00048828125f;
      #pragma unroll
      for (int mf = 0; mf < 4; ++mf) {
        const int abase = lg * AKG + (wm * 64 + mf * 16 + l15) * 8;
        f16x8 ahi = *reinterpret_cast<const f16x8*>(&As[cur][abase]);
        f16x8 axl = *reinterpret_cast<const f16x8*>(&As[cur][ASP + abase]);
        accA[mf][0] = __builtin_amdgcn_mfma_f32_16x16x32_f16(ahi, whi0_0, accA[mf][0], 0, 0, 0);
        accB[mf][0] = __builtin_amdgcn_mfma_f32_16x16x32_f16(ahi, wlp0_0, accB[mf][0], 0, 0, 0);
        accB[mf][0] = __builtin_amdgcn_mfma_f32_16x16x32_f16(axl, whi0_0, accB[mf][0], 0, 0, 0);
        accB[mf][0] = __builtin_amdgcn_mfma_f32_16x16x32_f16(axl, wlr0, accB[mf][0], 0, 0, 0);
        accA[mf][1] = __builtin_amdgcn_mfma_f32_16x16x32_f16(ahi, whi1_0, accA[mf][1], 0, 0, 0);
        accB[mf][1] = __builtin_amdgcn_mfma_f32_16x16x32_f16(ahi, wlp1_0, accB[mf][1], 0, 0, 0);
        accB[mf][1] = __builtin_amdgcn_mfma_f32_16x16x32_f16(axl, whi1_0, accB[mf][1], 0, 0, 0);
        accB[mf][1] = __builtin_amdgcn_mfma_f32_16x16x32_f16(axl, wlr1, accB[mf][1], 0, 0, 0);
      }
    }
    // ---- kw1 loads (latency hidden under kw0 MFMAs) + kw1 MFMAs
    {
      f16x8 whi0 = *reinterpret_cast<const f16x8*>(bbase + 512);
      f16x8 whi1 = *reinterpret_cast<const f16x8*>(bbase + 512 + 1024);
      f16x8 wlp0 = *reinterpret_cast<const f16x8*>(bbase + 512 + 16384);
      f16x8 wlp1 = *reinterpret_cast<const f16x8*>(bbase + 512 + 17408);
      f16x8 wlr0 = wlp0 * (f16)0.00048828125f;
      f16x8 wlr1 = wlp1 * (f16)0.00048828125f;
      #pragma unroll
      for (int mf = 0; mf < 4; ++mf) {
        const int abase = (4 + lg) * AKG + (wm * 64 + mf * 16 + l15) * 8;
        f16x8 ahi = *reinterpret_cast<const f16x8*>(&As[cur][abase]);
        f16x8 axl = *reinterpret_cast<const f16x8*>(&As[cur][ASP + abase]);
        accA[mf][0] = __builtin_amdgcn_mfma_f32_16x16x32_f16(ahi, whi0, accA[mf][0], 0, 0, 0);
        accB[mf][0] = __builtin_amdgcn_mfma_f32_16x16x32_f16(ahi, wlp0, accB[mf][0], 0, 0, 0);
        accB[mf][0] = __builtin_amdgcn_mfma_f32_16x16x32_f16(axl, whi0, accB[mf][0], 0, 0, 0);
        accB[mf][0] = __builtin_amdgcn_mfma_f32_16x16x32_f16(axl, wlr0, accB[mf][0], 0, 0, 0);
        accA[mf][1] = __builtin_amdgcn_mfma_f32_16x16x32_f16(ahi, whi1, accA[mf][1], 0, 0, 0);
        accB[mf][1] = __builtin_amdgcn_mfma_f32_16x16x32_f16(ahi, wlp1, accB[mf][1], 0, 0, 0);
        accB[mf][1] = __builtin_amdgcn_mfma_f32_16x16x32_f16(axl, whi1, accB[mf][1], 0, 0, 0);
        accB[mf][1] = __builtin_amdgcn_mfma_f32_16x16x32_f16(axl, wlr1, accB[mf][1], 0, 0, 0);
      }
    }
    __syncthreads();  // one barrier/step: A writes for s+1 visible, reads done
  }

  // finish stats: row owned by 8 threads (kg 0..7)
  rsum += __shfl_xor(rsum, 1); rsum += __shfl_xor(rsum, 2); rsum += __shfl_xor(rsum, 4);
  rsq  += __shfl_xor(rsq, 1);  rsq  += __shfl_xor(rsq, 2);  rsq  += __shfl_xor(rsq, 4);
  if ((tid & 7) == 0) {
    float mu  = rsum * (1.f / 1024.f);
    float var = rsq * (1.f / 1024.f) - mu * mu;
    smu[arow] = mu;
    srs[arow] = rsqrtf(var + 1e-5f);
  }
  __syncthreads();

  // epilogue: C/D col=l15, row=lg*4+reg. val = accA + accB/2048; LN affine +
  // GELU(exact) + W2 dot; 16-lane reduce; cross-wave via sred (fixed order).
  float s2[2], tb2[2], w2v[2];
  #pragma unroll
  for (int nf = 0; nf < 2; ++nf) {
    int col = wn * 32 + nf * 16 + l15;
    s2[nf] = S[col]; tb2[nf] = Tb[col]; w2v[nf] = W2[col];
  }
  #pragma unroll
  for (int mf = 0; mf < 4; ++mf) {
    const int rbase = wm * 64 + mf * 16 + lg * 4;
    #pragma unroll
    for (int reg = 0; reg < 4; ++reg) {
      const int row = rbase + reg;
      float mu = smu[row], rs = srs[row];
      float part = 0.f;
      #pragma unroll
      for (int nf = 0; nf < 2; ++nf) {
        float val = accA[mf][nf][reg] + accB[mf][nf][reg] * (1.f / 2048.f);
        float hpre = rs * val - rs * mu * s2[nf] + tb2[nf];
        float g = 0.5f * hpre * (1.f + erff(hpre * 0.70710678118654752f));
        part = fmaf(g, w2v[nf], part);
      }
      part += __shfl_xor(part, 1); part += __shfl_xor(part, 2);
      part += __shfl_xor(part, 4); part += __shfl_xor(part, 8);
      if (l15 == 0) sred[row][wn] = part;
    }
  }
  __syncthreads();
  if (tid < 128) {
    float sc = b2[0];
    #pragma unroll
    for (int w = 0; w < 8; ++w) sc += sred[tid][w];
    scores_out[RM + tid] = sc;
  }
}

// ---------------- topk: per-batch full bitonic sort of (descending score, ascending idx)
__global__ __launch_bounds__(1024) void topk_kernel(
    const float* __restrict__ scores, int k,
    float* __restrict__ idx_f, int* __restrict__ idx_i) {
  __shared__ unsigned long long keys[Lk];  // 64 KB
  const int b = blockIdx.x, t = threadIdx.x;
  for (int i = t; i < Lk; i += 1024) {
    unsigned u = __float_as_uint(scores[(size_t)b * Lk + i]);
    unsigned mono = (u & 0x80000000u) ? ~u : (u | 0x80000000u);  // ascending in value
    keys[i] = ((unsigned long long)(~mono) << 32) | (unsigned)i; // asc sort => desc score, asc idx
  }
  __syncthreads();
  for (int size = 2; size <= Lk; size <<= 1) {
    for (int stride = size >> 1; stride > 0; stride >>= 1) {
      for (int p = t; p < Lk / 2; p += 1024) {
        int lo = ((p & ~(stride - 1)) << 1) | (p & (stride - 1));
        int hi = lo + stride;
        bool up = ((lo & size) == 0);
        unsigned long long a = keys[lo], c = keys[hi];
        if ((a > c) == up) { keys[lo] = c; keys[hi] = a; }
      }
      __syncthreads();
    }
  }
  for (int i = t; i < k; i += 1024) {
    int id = (int)(keys[i] & 0xFFFFFFFFu);
    idx_f[(size_t)b * k + i] = (float)id;  // out buffer is fp32; indices exact in fp32
    idx_i[(size_t)b * k + i] = id;
  }
}

// ---------------- gather: one block per selected row, 4 KB float4 copy
__global__ __launch_bounds__(256) void gather_kernel(
    const float* __restrict__ F, const int* __restrict__ idx,
    float* __restrict__ out, int k) {
  int row = blockIdx.x;          // 0 .. 8*k-1
  int b = row / k;
  int id = idx[row];
  const float4* src = reinterpret_cast<const float4*>(F + ((size_t)b * Lk + id) * Dk);
  float4* dst = reinterpret_cast<float4*>(out + (size_t)row * Dk);
  dst[threadIdx.x] = src[threadIdx.x];
}

extern "C" void kernel_launch(void* const* d_in, const int* in_sizes, int n_in,
                              void* d_out, int out_size, void* d_ws, size_t ws_size,
                              hipStream_t stream) {
  const float* F     = (const float*)d_in[0];
  const float* gamma = (const float*)d_in[1];
  const float* beta  = (const float*)d_in[2];
  const float* W1    = (const float*)d_in[3];
  const float* b1    = (const float*)d_in[4];
  const float* W2    = (const float*)d_in[5];
  const float* b2    = (const float*)d_in[6];
  // k lives on device; derive on host from out_size = 8*k*1024 + 8*8192 + 8*k
  int k = (out_size - Bk * Lk) / (Bk * Dk + Bk);   // = 512

  float* out_sel = (float*)d_out;                       // [8, k, 1024]
  float* out_sc  = out_sel + (size_t)Bk * k * Dk;       // [8, 8192]
  float* out_idx = out_sc + (size_t)Bk * Lk;            // [8, k] as float

  // ws: W1F f16[524288] (1MB) | Spart f32[16384] | Tpart f32[16384] |
  //     S f32[256] | Tb f32[256] | idxi i32[8*k]
  f16*   W1F   = (f16*)d_ws;
  float* Spart = (float*)((char*)d_ws + 524288 * sizeof(f16));
  float* Tpart = Spart + 16384;
  float* Sp    = Tpart + 16384;
  float* Tbp   = Sp + Hk;
  int*   idxi  = (int*)(Tbp + Hk);

  hipLaunchKernelGGL(prep_split,   dim3(64),         dim3(1024), 0, stream,
                     W1, gamma, beta, W1F, Spart, Tpart);
  hipLaunchKernelGGL(prep_combine, dim3(1),          dim3(Hk),   0, stream,
                     Spart, Tpart, b1, Sp, Tbp);
  hipLaunchKernelGGL(scores_mfma,  dim3(MTOT / 128), dim3(1024), 0, stream,
                     F, W1F, Sp, Tbp, W2, b2, out_sc);
  hipLaunchKernelGGL(topk_kernel,  dim3(Bk),         dim3(1024), 0, stream,
                     out_sc, k, out_idx, idxi);
  hipLaunchKernelGGL(gather_kernel, dim3(Bk * k),    dim3(256),  0, stream,
                     F, idxi, out_sel, k);
}

// Round 9
// 187.550 us; speedup vs baseline: 51.7669x; 1.1618x over previous
//
#include <hip/hip_runtime.h>
#include <math.h>

#define Dk 1024
#define Hk 256
#define Lk 8192
#define Bk 8
#define MTOT (Bk*Lk)   // 65536 rows

typedef _Float16 f16;
typedef __attribute__((ext_vector_type(8))) _Float16 f16x8;
typedef __attribute__((ext_vector_type(4))) float f32x4;
typedef unsigned long long u64;

#define AKG 520             // padded kg stride (64 rows * 8 + 8): banks 4 apart per kg
#define ASP (8*AKG)         // split stride
#define ABUF (2*ASP)        // elems per LDS buffer

// ---------------- prep_split: W1 -> gamma-folded fp16 2-way split (hi, lo*2048)
// in MFMA-fragment order, PLUS partials for S = gamma@W1, T = beta@W1.
// Layout: W1F[ks(16)][sp(2)][nf(16)][kg(8)][n(16)][k(8)], d=ks*64+kg*8+k, h=nf*16+n.
__global__ __launch_bounds__(1024) void prep_split(
    const float* __restrict__ W1, const float* __restrict__ gamma,
    const float* __restrict__ beta, f16* __restrict__ W1F,
    float* __restrict__ Spart, float* __restrict__ Tpart) {
  __shared__ float ps[1024], pt[1024];
  const int b = blockIdx.x, t = threadIdx.x;
  float sa = 0.f, ta = 0.f;
  #pragma unroll
  for (int j = 0; j < 4; ++j) {
    int idx = j * 65536 + b * 1024 + t;
    int d = idx >> 8, h = idx & 255;
    float w = W1[idx];
    float g = gamma[d];
    sa = fmaf(g, w, sa);
    ta = fmaf(beta[d], w, ta);
    float wg = g * w;                       // gamma folded into W1
    f16 whi = (f16)wg;
    f16 wlp = (f16)((wg - (float)whi) * 2048.f);   // scaled lo: stays fp16-normal
    int ks = d >> 6, kg = (d >> 3) & 7, kk = d & 7;
    int nf = h >> 4, nn = h & 15;
    size_t base = ((((size_t)ks * 2) * 16 + nf) * 8 + kg) * 128 + nn * 8 + kk;
    W1F[base] = whi;
    W1F[base + 16384] = wlp;                // sp stride = 16*8*128
  }
  ps[t] = sa; pt[t] = ta;
  __syncthreads();
  if (t < 256) {
    Spart[b * 256 + t] = ps[t] + ps[t + 256] + ps[t + 512] + ps[t + 768];
    Tpart[b * 256 + t] = pt[t] + pt[t + 256] + pt[t + 512] + pt[t + 768];
  }
}

__global__ __launch_bounds__(256) void prep_combine(
    const float* __restrict__ Spart, const float* __restrict__ Tpart,
    const float* __restrict__ b1, float* __restrict__ S, float* __restrict__ Tb) {
  int j = threadIdx.x;
  float s = 0.f, t = 0.f;
  for (int b = 0; b < 64; ++b) { s += Spart[b * 256 + j]; t += Tpart[b * 256 + j]; }
  S[j] = s;
  Tb[j] = t + b1[j];
}

// ---------------- scores: fused LN + Linear(1024->256) + GELU + Linear(256->1)
// fp16 2-way-split MFMA (4 products, dual acc). BM=64, BN=256, BK=64.
// 512 threads = 8 waves (2M x 4N), wave tile 32x64. LDS ~35KB + 128 regs
// -> EXACTLY 2 blocks/CU: independent barriers => when one block is in its
// staging/VALU phase the other feeds the MFMA pipe (phase diversity that the
// single-block 16-wave lockstep could not give). FP order per output
// identical to round 8 => bit-identical scores.
__global__ __launch_bounds__(512, 2) void scores_mfma(
    const float* __restrict__ F, const f16* __restrict__ W1F,
    const float* __restrict__ S, const float* __restrict__ Tb,
    const float* __restrict__ W2, const float* __restrict__ b2,
    float* __restrict__ scores_out) {
  __shared__ f16 As[2][ABUF];      // 2 x 16.6KB: [sp(2)][kg(8)][row(64)][k8]
  __shared__ float smu[64], srs[64];
  __shared__ float sred[64][4];

  const int tid = threadIdx.x;
  const int RM = blockIdx.x * 64;
  const int wid = tid >> 6, lane = tid & 63;
  const int wm = wid & 1, wn = wid >> 1;     // wm: 32-row half, wn 0..3: 64-col slice
  const int lg = lane >> 4, l15 = lane & 15;

  // A staging: thread -> (row 0..63, one k8-group of the 64-wide K step)
  const int arow = tid >> 3, kg = tid & 7;
  const float* Aptr = F + (size_t)(RM + arow) * Dk + kg * 8;

  // per-thread fragment bases
  const int aoff0 = lg * AKG + (wm * 32 + l15) * 8;          // A frag (sp0,kw0,mf0)
  const int bwoff = (wn * 4) * 1024 + lg * 128 + l15 * 8;    // B frag (nf0,sp0,kw0)

  f32x4 accA[2][4], accB[2][4];
  #pragma unroll
  for (int i = 0; i < 2; ++i)
    #pragma unroll
    for (int j = 0; j < 4; ++j) {
      accA[i][j] = (f32x4){0.f, 0.f, 0.f, 0.f};
      accB[i][j] = (f32x4){0.f, 0.f, 0.f, 0.f};
    }

  float rsum = 0.f, rsq = 0.f;

  // stats + fp16 2-way split of 8 raw elems -> two b128 LDS writes
#define SPLIT_STORE(buf, av0, av1)                                             \
  {                                                                            \
    float xx[8] = {av0.x, av0.y, av0.z, av0.w, av1.x, av1.y, av1.z, av1.w};    \
    f16x8 vhi, vlo;                                                            \
    _Pragma("unroll")                                                          \
    for (int e = 0; e < 8; ++e) {                                              \
      float x = xx[e];                                                         \
      rsum += x; rsq = fmaf(x, x, rsq);                                        \
      f16 hi = (f16)x;                                                         \
      vhi[e] = hi;                                                             \
      vlo[e] = (f16)((x - (float)hi) * 2048.f);                                \
    }                                                                          \
    *reinterpret_cast<f16x8*>(&As[buf][kg * AKG + arow * 8]) = vhi;            \
    *reinterpret_cast<f16x8*>(&As[buf][ASP + kg * AKG + arow * 8]) = vlo;      \
  }

  // prologue: stage tile 0, prefetch raw tile 1
  float4 av0 = *reinterpret_cast<const float4*>(Aptr);
  float4 av1 = *reinterpret_cast<const float4*>(Aptr + 4);
  SPLIT_STORE(0, av0, av1)
  av0 = *reinterpret_cast<const float4*>(Aptr + 64);
  av1 = *reinterpret_cast<const float4*>(Aptr + 68);
  __syncthreads();

  for (int s = 0; s < 16; ++s) {
    const int cur = s & 1;
    const f16* bstep = W1F + (size_t)s * 32768 + bwoff;
    f16x8 whi[4], wlp[4];
    // ---- kw0 B loads first (L2 latency hidden by split below / other block)
    #pragma unroll
    for (int nf = 0; nf < 4; ++nf) {
      whi[nf] = *reinterpret_cast<const f16x8*>(bstep + nf * 1024);
      wlp[nf] = *reinterpret_cast<const f16x8*>(bstep + nf * 1024 + 16384);
    }
    // ---- split tile s+1 (pure VALU + LDS writes)
    if (s < 15) {
      SPLIT_STORE(cur ^ 1, av0, av1)
      if (s < 14) {
        av0 = *reinterpret_cast<const float4*>(Aptr + (s + 2) * 64);
        av1 = *reinterpret_cast<const float4*>(Aptr + (s + 2) * 64 + 4);
      }
    }
    // ---- kw0 MFMAs
    {
      const f16* ab = &As[cur][aoff0];
      f16x8 ahi0 = *reinterpret_cast<const f16x8*>(ab);
      f16x8 ahi1 = *reinterpret_cast<const f16x8*>(ab + 128);
      f16x8 axl0 = *reinterpret_cast<const f16x8*>(ab + ASP);
      f16x8 axl1 = *reinterpret_cast<const f16x8*>(ab + ASP + 128);
      #pragma unroll
      for (int nf = 0; nf < 4; ++nf) {
        f16x8 wlr = wlp[nf] * (f16)0.00048828125f;   // exact *2^-11
        accA[0][nf] = __builtin_amdgcn_mfma_f32_16x16x32_f16(ahi0, whi[nf], accA[0][nf], 0, 0, 0);
        accB[0][nf] = __builtin_amdgcn_mfma_f32_16x16x32_f16(ahi0, wlp[nf], accB[0][nf], 0, 0, 0);
        accB[0][nf] = __builtin_amdgcn_mfma_f32_16x16x32_f16(axl0, whi[nf], accB[0][nf], 0, 0, 0);
        accB[0][nf] = __builtin_amdgcn_mfma_f32_16x16x32_f16(axl0, wlr, accB[0][nf], 0, 0, 0);
        accA[1][nf] = __builtin_amdgcn_mfma_f32_16x16x32_f16(ahi1, whi[nf], accA[1][nf], 0, 0, 0);
        accB[1][nf] = __builtin_amdgcn_mfma_f32_16x16x32_f16(ahi1, wlp[nf], accB[1][nf], 0, 0, 0);
        accB[1][nf] = __builtin_amdgcn_mfma_f32_16x16x32_f16(axl1, whi[nf], accB[1][nf], 0, 0, 0);
        accB[1][nf] = __builtin_amdgcn_mfma_f32_16x16x32_f16(axl1, wlr, accB[1][nf], 0, 0, 0);
      }
    }
    // ---- kw1 loads + MFMAs
    #pragma unroll
    for (int nf = 0; nf < 4; ++nf) {
      whi[nf] = *reinterpret_cast<const f16x8*>(bstep + nf * 1024 + 512);
      wlp[nf] = *reinterpret_cast<const f16x8*>(bstep + nf * 1024 + 512 + 16384);
    }
    {
      const f16* ab = &As[cur][aoff0 + 4 * AKG];
      f16x8 ahi0 = *reinterpret_cast<const f16x8*>(ab);
      f16x8 ahi1 = *reinterpret_cast<const f16x8*>(ab + 128);
      f16x8 axl0 = *reinterpret_cast<const f16x8*>(ab + ASP);
      f16x8 axl1 = *reinterpret_cast<const f16x8*>(ab + ASP + 128);
      #pragma unroll
      for (int nf = 0; nf < 4; ++nf) {
        f16x8 wlr = wlp[nf] * (f16)0.00048828125f;
        accA[0][nf] = __builtin_amdgcn_mfma_f32_16x16x32_f16(ahi0, whi[nf], accA[0][nf], 0, 0, 0);
        accB[0][nf] = __builtin_amdgcn_mfma_f32_16x16x32_f16(ahi0, wlp[nf], accB[0][nf], 0, 0, 0);
        accB[0][nf] = __builtin_amdgcn_mfma_f32_16x16x32_f16(axl0, whi[nf], accB[0][nf], 0, 0, 0);
        accB[0][nf] = __builtin_amdgcn_mfma_f32_16x16x32_f16(axl0, wlr, accB[0][nf], 0, 0, 0);
        accA[1][nf] = __builtin_amdgcn_mfma_f32_16x16x32_f16(ahi1, whi[nf], accA[1][nf], 0, 0, 0);
        accB[1][nf] = __builtin_amdgcn_mfma_f32_16x16x32_f16(ahi1, wlp[nf], accB[1][nf], 0, 0, 0);
        accB[1][nf] = __builtin_amdgcn_mfma_f32_16x16x32_f16(axl1, whi[nf], accB[1][nf], 0, 0, 0);
        accB[1][nf] = __builtin_amdgcn_mfma_f32_16x16x32_f16(axl1, wlr, accB[1][nf], 0, 0, 0);
      }
    }
    __syncthreads();  // one barrier/step
  }

  // finish stats: row owned by 8 threads (kg 0..7)
  rsum += __shfl_xor(rsum, 1); rsum += __shfl_xor(rsum, 2); rsum += __shfl_xor(rsum, 4);
  rsq  += __shfl_xor(rsq, 1);  rsq  += __shfl_xor(rsq, 2);  rsq  += __shfl_xor(rsq, 4);
  if ((tid & 7) == 0) {
    float mu  = rsum * (1.f / 1024.f);
    float var = rsq * (1.f / 1024.f) - mu * mu;
    smu[arow] = mu;
    srs[arow] = rsqrtf(var + 1e-5f);
  }
  __syncthreads();

  // epilogue: C/D col=l15, row=lg*4+reg. val = accA + accB/2048; LN affine +
  // GELU(exact) + W2 dot; 16-lane reduce; cross-wave via sred (fixed order).
  float s2[4], tb2[4], w2v[4];
  #pragma unroll
  for (int nf = 0; nf < 4; ++nf) {
    int col = (wn * 4 + nf) * 16 + l15;
    s2[nf] = S[col]; tb2[nf] = Tb[col]; w2v[nf] = W2[col];
  }
  #pragma unroll
  for (int mf = 0; mf < 2; ++mf) {
    const int rbase = wm * 32 + mf * 16 + lg * 4;
    #pragma unroll
    for (int reg = 0; reg < 4; ++reg) {
      const int row = rbase + reg;
      float mu = smu[row], rs = srs[row];
      float part = 0.f;
      #pragma unroll
      for (int nf = 0; nf < 4; ++nf) {
        float val = accA[mf][nf][reg] + accB[mf][nf][reg] * (1.f / 2048.f);
        float hpre = rs * val - rs * mu * s2[nf] + tb2[nf];
        float g = 0.5f * hpre * (1.f + erff(hpre * 0.70710678118654752f));
        part = fmaf(g, w2v[nf], part);
      }
      part += __shfl_xor(part, 1); part += __shfl_xor(part, 2);
      part += __shfl_xor(part, 4); part += __shfl_xor(part, 8);
      if (l15 == 0) sred[row][wn] = part;
    }
  }
  __syncthreads();
  if (tid < 64) {
    float sc = b2[0] + sred[tid][0] + sred[tid][1] + sred[tid][2] + sred[tid][3];
    scores_out[RM + tid] = sc;
  }
}

// ---------------- topk stage 1: 64 blocks, each sorts a 1024-score chunk
// (keys ascending = scores descending, idx-asc ties) and keeps top 512.
__global__ __launch_bounds__(512) void topk_stage1(
    const float* __restrict__ scores, u64* __restrict__ kout) {
  __shared__ u64 keys[1024];
  const int blk = blockIdx.x;
  const int batch = blk >> 3, chunk = blk & 7;
  const int t = threadIdx.x;
  #pragma unroll
  for (int j = 0; j < 2; ++j) {
    int i = t + j * 512;
    int gi = chunk * 1024 + i;                 // within-batch index
    unsigned u = __float_as_uint(scores[(size_t)batch * Lk + gi]);
    unsigned mono = (u & 0x80000000u) ? ~u : (u | 0x80000000u);
    keys[i] = ((u64)(~mono) << 32) | (unsigned)gi;
  }
  __syncthreads();
  for (int size = 2; size <= 1024; size <<= 1) {
    for (int stride = size >> 1; stride > 0; stride >>= 1) {
      int lo = ((t & ~(stride - 1)) << 1) | (t & (stride - 1));
      int hi = lo + stride;
      bool up = ((lo & size) == 0);
      u64 a = keys[lo], c = keys[hi];
      if ((a > c) == up) { keys[lo] = c; keys[hi] = a; }
      __syncthreads();
    }
  }
  kout[(size_t)blk * 512 + t] = keys[t];       // smallest 512 keys = top scores
}

// ---------------- topk stage 2: 8 blocks, tree-merge 8 sorted 512-lists.
// merge(two asc 512): m[i] = min(A[i], B[511-i]) (bitonic) -> 9-stage merge.
__global__ __launch_bounds__(512) void topk_stage2(
    const u64* __restrict__ kin, int k,
    float* __restrict__ idx_f, int* __restrict__ idx_i) {
  __shared__ u64 kk[4096];
  __shared__ u64 tmp[2048];
  const int b = blockIdx.x, t = threadIdx.x;
  #pragma unroll
  for (int j = 0; j < 8; ++j) kk[t + j * 512] = kin[(size_t)b * 4096 + t + j * 512];
  __syncthreads();
  // level 0: kk (8 runs) -> tmp (4 runs)
  #pragma unroll
  for (int j = 0; j < 4; ++j) {
    u64 a = kk[j * 1024 + t];
    u64 c = kk[j * 1024 + 512 + (511 - t)];
    tmp[j * 512 + t] = a < c ? a : c;
  }
  __syncthreads();
  for (int stride = 256; stride > 0; stride >>= 1) {
    #pragma unroll
    for (int w = 0; w < 2; ++w) {
      int p = t + w * 512;                     // 1024 disjoint pairs
      int r = p >> 8, q = p & 255;
      int lo = r * 512 + (((q & ~(stride - 1)) << 1) | (q & (stride - 1)));
      u64 a = tmp[lo], c = tmp[lo + stride];
      if (a > c) { tmp[lo] = c; tmp[lo + stride] = a; }
    }
    __syncthreads();
  }
  // level 1: tmp (4 runs) -> kk (2 runs)
  if (t < 512) {
    int j = t >> 8 >> 1;  // dummy keep shape
  }
  #pragma unroll
  for (int j = 0; j < 2; ++j) {
    u64 a = tmp[j * 1024 + t];
    u64 c = tmp[j * 1024 + 512 + (511 - t)];
    kk[j * 512 + t] = a < c ? a : c;
  }
  __syncthreads();
  for (int stride = 256; stride > 0; stride >>= 1) {
    int r = t >> 8, q = t & 255;               // 512 pairs over 2 runs
    int lo = r * 512 + (((q & ~(stride - 1)) << 1) | (q & (stride - 1)));
    u64 a = kk[lo], c = kk[lo + stride];
    if (a > c) { kk[lo] = c; kk[lo + stride] = a; }
    __syncthreads();
  }
  // level 2: kk (2 runs) -> tmp[0..512)
  {
    u64 a = kk[t];
    u64 c = kk[512 + (511 - t)];
    tmp[t] = a < c ? a : c;
  }
  __syncthreads();
  for (int stride = 256; stride > 0; stride >>= 1) {
    if (t < 256) {
      int lo = ((t & ~(stride - 1)) << 1) | (t & (stride - 1));
      u64 a = tmp[lo], c = tmp[lo + stride];
      if (a > c) { tmp[lo] = c; tmp[lo + stride] = a; }
    }
    __syncthreads();
  }
  if (t < k) {
    int id = (int)(tmp[t] & 0xFFFFFFFFu);
    idx_f[(size_t)b * k + t] = (float)id;
    idx_i[(size_t)b * k + t] = id;
  }
}

// ---------------- gather: one block per selected row, 4 KB float4 copy
__global__ __launch_bounds__(256) void gather_kernel(
    const float* __restrict__ F, const int* __restrict__ idx,
    float* __restrict__ out, int k) {
  int row = blockIdx.x;          // 0 .. 8*k-1
  int b = row / k;
  int id = idx[row];
  const float4* src = reinterpret_cast<const float4*>(F + ((size_t)b * Lk + id) * Dk);
  float4* dst = reinterpret_cast<float4*>(out + (size_t)row * Dk);
  dst[threadIdx.x] = src[threadIdx.x];
}

extern "C" void kernel_launch(void* const* d_in, const int* in_sizes, int n_in,
                              void* d_out, int out_size, void* d_ws, size_t ws_size,
                              hipStream_t stream) {
  const float* F     = (const float*)d_in[0];
  const float* gamma = (const float*)d_in[1];
  const float* beta  = (const float*)d_in[2];
  const float* W1    = (const float*)d_in[3];
  const float* b1    = (const float*)d_in[4];
  const float* W2    = (const float*)d_in[5];
  const float* b2    = (const float*)d_in[6];
  // k lives on device; derive on host from out_size = 8*k*1024 + 8*8192 + 8*k
  int k = (out_size - Bk * Lk) / (Bk * Dk + Bk);   // = 512

  float* out_sel = (float*)d_out;                       // [8, k, 1024]
  float* out_sc  = out_sel + (size_t)Bk * k * Dk;       // [8, 8192]
  float* out_idx = out_sc + (size_t)Bk * Lk;            // [8, k] as float

  // ws: W1F f16[524288] (1MB) | kout u64[32768] (256KB) | Spart f32[16384] |
  //     Tpart f32[16384] | S f32[256] | Tb f32[256] | idxi i32[8*k]
  f16*   W1F   = (f16*)d_ws;
  u64*   kout  = (u64*)((char*)d_ws + (1 << 20));
  float* Spart = (float*)((char*)kout + 262144);
  float* Tpart = Spart + 16384;
  float* Sp    = Tpart + 16384;
  float* Tbp   = Sp + Hk;
  int*   idxi  = (int*)(Tbp + Hk);

  hipLaunchKernelGGL(prep_split,   dim3(64),        dim3(1024), 0, stream,
                     W1, gamma, beta, W1F, Spart, Tpart);
  hipLaunchKernelGGL(prep_combine, dim3(1),         dim3(Hk),   0, stream,
                     Spart, Tpart, b1, Sp, Tbp);
  hipLaunchKernelGGL(scores_mfma,  dim3(MTOT / 64), dim3(512),  0, stream,
                     F, W1F, Sp, Tbp, W2, b2, out_sc);
  hipLaunchKernelGGL(topk_stage1,  dim3(64),        dim3(512),  0, stream,
                     out_sc, kout);
  hipLaunchKernelGGL(topk_stage2,  dim3(Bk),        dim3(512),  0, stream,
                     kout, k, out_idx, idxi);
  hipLaunchKernelGGL(gather_kernel, dim3(Bk * k),   dim3(256),  0, stream,
                     F, idxi, out_sel, k);
}

// Round 10
// 161.841 us; speedup vs baseline: 59.9905x; 1.1589x over previous
//
#include <hip/hip_runtime.h>
#include <math.h>

#define Dk 1024
#define Hk 256
#define Lk 8192
#define Bk 8
#define MTOT (Bk*Lk)   // 65536 rows

typedef _Float16 f16;
typedef __attribute__((ext_vector_type(8))) _Float16 f16x8;
typedef __attribute__((ext_vector_type(4))) float f32x4;
typedef unsigned long long u64;

#define AKG 520             // padded kg stride (elems)
#define ASP (8*AKG)         // split stride
#define ABUF (2*ASP)        // elems per LDS buffer

// ---------------- prep_split: W1 -> gamma-folded fp16 2-way split (hi, lo*2048)
// in MFMA-fragment order, PLUS partials for S = gamma@W1, T = beta@W1.
// Layout: W1F[ks(16)][sp(2)][nf(16)][kg(8)][n(16)][k(8)], d=ks*64+kg*8+k, h=nf*16+n.
__global__ __launch_bounds__(1024) void prep_split(
    const float* __restrict__ W1, const float* __restrict__ gamma,
    const float* __restrict__ beta, f16* __restrict__ W1F,
    float* __restrict__ Spart, float* __restrict__ Tpart) {
  __shared__ float ps[1024], pt[1024];
  const int b = blockIdx.x, t = threadIdx.x;
  float sa = 0.f, ta = 0.f;
  #pragma unroll
  for (int j = 0; j < 4; ++j) {
    int idx = j * 65536 + b * 1024 + t;
    int d = idx >> 8, h = idx & 255;
    float w = W1[idx];
    float g = gamma[d];
    sa = fmaf(g, w, sa);
    ta = fmaf(beta[d], w, ta);
    float wg = g * w;                       // gamma folded into W1
    f16 whi = (f16)wg;
    f16 wlp = (f16)((wg - (float)whi) * 2048.f);   // scaled lo: stays fp16-normal
    int ks = d >> 6, kg = (d >> 3) & 7, kk = d & 7;
    int nf = h >> 4, nn = h & 15;
    size_t base = ((((size_t)ks * 2) * 16 + nf) * 8 + kg) * 128 + nn * 8 + kk;
    W1F[base] = whi;
    W1F[base + 16384] = wlp;                // sp stride = 16*8*128
  }
  ps[t] = sa; pt[t] = ta;
  __syncthreads();
  if (t < 256) {
    Spart[b * 256 + t] = ps[t] + ps[t + 256] + ps[t + 512] + ps[t + 768];
    Tpart[b * 256 + t] = pt[t] + pt[t + 256] + pt[t + 512] + pt[t + 768];
  }
}

__global__ __launch_bounds__(256) void prep_combine(
    const float* __restrict__ Spart, const float* __restrict__ Tpart,
    const float* __restrict__ b1, float* __restrict__ S, float* __restrict__ Tb) {
  int j = threadIdx.x;
  float s = 0.f, t = 0.f;
  for (int b = 0; b < 64; ++b) { s += Spart[b * 256 + j]; t += Tpart[b * 256 + j]; }
  S[j] = s;
  Tb[j] = t + b1[j];
}

// 3-product split-fp16 triple: accA += ah*wh; accB += ah*wl + ax*wh
// (ax, wl both pre-scaled by 2048; dropped ax*wl/2048 term ~1e-6 rel err)
#define MM3(aA, aB, ah, ax, wh, wl)                                            \
  aA = __builtin_amdgcn_mfma_f32_16x16x32_f16(ah, wh, aA, 0, 0, 0);            \
  aB = __builtin_amdgcn_mfma_f32_16x16x32_f16(ah, wl, aB, 0, 0, 0);            \
  aB = __builtin_amdgcn_mfma_f32_16x16x32_f16(ax, wh, aB, 0, 0, 0);

// ---------------- scores: fused LN + Linear(1024->256) + GELU + Linear(256->1)
// fp16 2-way-split MFMA, 3 products, dual acc. BM=64, BN=256, BK=64.
// 512 threads = 8 waves (2M x 4N), wave tile 32x64. acc = 64 AGPR; arch VGPR
// capped at 64 by __launch_bounds__(512,4) (observed mapping: cap = 256/N).
// Total 128 regs/thread -> TWO independent blocks/CU (16 waves) whose
// barriers interleave: one block's staging VALU overlaps the other's MFMA.
__global__ __launch_bounds__(512, 4) void scores_mfma(
    const float* __restrict__ F, const f16* __restrict__ W1F,
    const float* __restrict__ S, const float* __restrict__ Tb,
    const float* __restrict__ W2, const float* __restrict__ b2,
    float* __restrict__ scores_out) {
  __shared__ f16 As[2][ABUF];      // 2 x 16.6KB: [sp(2)][kg(8)][row(64)][k8]
  __shared__ float smu[64], srs[64];
  __shared__ float sred[64][4];

  const int tid = threadIdx.x;
  const int RM = blockIdx.x * 64;
  const int wid = tid >> 6, lane = tid & 63;
  const int wm = wid & 1, wn = wid >> 1;     // wm: 32-row half, wn 0..3: 64-col slice
  const int lg = lane >> 4, l15 = lane & 15;

  // A staging: thread -> (row 0..63, one k8-group of the 64-wide K step)
  const int arow = tid >> 3, kg = tid & 7;
  const float* Aptr = F + (size_t)(RM + arow) * Dk + kg * 8;

  const int aoff0 = lg * AKG + (wm * 32 + l15) * 8;          // A frag base (kw0)
  const int bwoff = (wn * 4) * 1024 + lg * 128 + l15 * 8;    // B frag base (nf0,kw0)

  f32x4 accA[2][4], accB[2][4];
  #pragma unroll
  for (int i = 0; i < 2; ++i)
    #pragma unroll
    for (int j = 0; j < 4; ++j) {
      accA[i][j] = (f32x4){0.f, 0.f, 0.f, 0.f};
      accB[i][j] = (f32x4){0.f, 0.f, 0.f, 0.f};
    }

  float rsum = 0.f, rsq = 0.f;

  // stats + fp16 2-way split of 8 raw elems -> two b128 LDS writes
#define SPLIT_STORE(buf, av0, av1)                                             \
  {                                                                            \
    f16x8 vhi, vlo;                                                            \
    _Pragma("unroll")                                                          \
    for (int e = 0; e < 8; ++e) {                                              \
      float x = (e < 4) ? ((e == 0) ? av0.x : (e == 1) ? av0.y                 \
                           : (e == 2) ? av0.z : av0.w)                         \
                        : ((e == 4) ? av1.x : (e == 5) ? av1.y                 \
                           : (e == 6) ? av1.z : av1.w);                        \
      rsum += x; rsq = fmaf(x, x, rsq);                                        \
      f16 hi = (f16)x;                                                         \
      vhi[e] = hi;                                                             \
      vlo[e] = (f16)((x - (float)hi) * 2048.f);                                \
    }                                                                          \
    *reinterpret_cast<f16x8*>(&As[buf][kg * AKG + arow * 8]) = vhi;            \
    *reinterpret_cast<f16x8*>(&As[buf][ASP + kg * AKG + arow * 8]) = vlo;      \
  }

  // prologue: stage tile 0, prefetch raw tile 1
  float4 av0 = *reinterpret_cast<const float4*>(Aptr);
  float4 av1 = *reinterpret_cast<const float4*>(Aptr + 4);
  SPLIT_STORE(0, av0, av1)
  av0 = *reinterpret_cast<const float4*>(Aptr + 64);
  av1 = *reinterpret_cast<const float4*>(Aptr + 68);
  __syncthreads();

  for (int s = 0; s < 16; ++s) {
    const int cur = s & 1;
    const f16* bs = W1F + (size_t)s * 32768 + bwoff;

    // ======== kw0 ========
    {
      // B np0 loads issued first (L2 latency hidden by split below)
      f16x8 wh0 = *reinterpret_cast<const f16x8*>(bs);
      f16x8 wh1 = *reinterpret_cast<const f16x8*>(bs + 1024);
      f16x8 wl0 = *reinterpret_cast<const f16x8*>(bs + 16384);
      f16x8 wl1 = *reinterpret_cast<const f16x8*>(bs + 17408);
      // A kw0 fragments
      const f16* ab = &As[cur][aoff0];
      f16x8 ahi0 = *reinterpret_cast<const f16x8*>(ab);
      f16x8 ahi1 = *reinterpret_cast<const f16x8*>(ab + 128);
      f16x8 axl0 = *reinterpret_cast<const f16x8*>(ab + ASP);
      f16x8 axl1 = *reinterpret_cast<const f16x8*>(ab + ASP + 128);
      // split tile s+1 (pure VALU + LDS writes; overlaps the loads above)
      if (s < 15) {
        SPLIT_STORE(cur ^ 1, av0, av1)
        if (s < 14) {
          av0 = *reinterpret_cast<const float4*>(Aptr + (s + 2) * 64);
          av1 = *reinterpret_cast<const float4*>(Aptr + (s + 2) * 64 + 4);
        }
      }
      MM3(accA[0][0], accB[0][0], ahi0, axl0, wh0, wl0)
      MM3(accA[1][0], accB[1][0], ahi1, axl1, wh0, wl0)
      MM3(accA[0][1], accB[0][1], ahi0, axl0, wh1, wl1)
      MM3(accA[1][1], accB[1][1], ahi1, axl1, wh1, wl1)
      // B np1
      wh0 = *reinterpret_cast<const f16x8*>(bs + 2048);
      wh1 = *reinterpret_cast<const f16x8*>(bs + 3072);
      wl0 = *reinterpret_cast<const f16x8*>(bs + 2048 + 16384);
      wl1 = *reinterpret_cast<const f16x8*>(bs + 3072 + 16384);
      MM3(accA[0][2], accB[0][2], ahi0, axl0, wh0, wl0)
      MM3(accA[1][2], accB[1][2], ahi1, axl1, wh0, wl0)
      MM3(accA[0][3], accB[0][3], ahi0, axl0, wh1, wl1)
      MM3(accA[1][3], accB[1][3], ahi1, axl1, wh1, wl1)
    }
    // ======== kw1 ========
    {
      f16x8 wh0 = *reinterpret_cast<const f16x8*>(bs + 512);
      f16x8 wh1 = *reinterpret_cast<const f16x8*>(bs + 512 + 1024);
      f16x8 wl0 = *reinterpret_cast<const f16x8*>(bs + 512 + 16384);
      f16x8 wl1 = *reinterpret_cast<const f16x8*>(bs + 512 + 17408);
      const f16* ab = &As[cur][aoff0 + 4 * AKG];
      f16x8 ahi0 = *reinterpret_cast<const f16x8*>(ab);
      f16x8 ahi1 = *reinterpret_cast<const f16x8*>(ab + 128);
      f16x8 axl0 = *reinterpret_cast<const f16x8*>(ab + ASP);
      f16x8 axl1 = *reinterpret_cast<const f16x8*>(ab + ASP + 128);
      MM3(accA[0][0], accB[0][0], ahi0, axl0, wh0, wl0)
      MM3(accA[1][0], accB[1][0], ahi1, axl1, wh0, wl0)
      MM3(accA[0][1], accB[0][1], ahi0, axl0, wh1, wl1)
      MM3(accA[1][1], accB[1][1], ahi1, axl1, wh1, wl1)
      wh0 = *reinterpret_cast<const f16x8*>(bs + 512 + 2048);
      wh1 = *reinterpret_cast<const f16x8*>(bs + 512 + 3072);
      wl0 = *reinterpret_cast<const f16x8*>(bs + 512 + 2048 + 16384);
      wl1 = *reinterpret_cast<const f16x8*>(bs + 512 + 3072 + 16384);
      MM3(accA[0][2], accB[0][2], ahi0, axl0, wh0, wl0)
      MM3(accA[1][2], accB[1][2], ahi1, axl1, wh0, wl0)
      MM3(accA[0][3], accB[0][3], ahi0, axl0, wh1, wl1)
      MM3(accA[1][3], accB[1][3], ahi1, axl1, wh1, wl1)
    }
    __syncthreads();  // one barrier/step
  }

  // finish stats: row owned by 8 threads (kg 0..7)
  rsum += __shfl_xor(rsum, 1); rsum += __shfl_xor(rsum, 2); rsum += __shfl_xor(rsum, 4);
  rsq  += __shfl_xor(rsq, 1);  rsq  += __shfl_xor(rsq, 2);  rsq  += __shfl_xor(rsq, 4);
  if ((tid & 7) == 0) {
    float mu  = rsum * (1.f / 1024.f);
    float var = rsq * (1.f / 1024.f) - mu * mu;
    smu[arow] = mu;
    srs[arow] = rsqrtf(var + 1e-5f);
  }
  __syncthreads();

  // epilogue: C/D col=l15, row=lg*4+reg. val = accA + accB/2048; LN affine +
  // GELU(exact) + W2 dot; 16-lane reduce; cross-wave via sred (fixed order).
  float s2[4], tb2[4], w2v[4];
  #pragma unroll
  for (int nf = 0; nf < 4; ++nf) {
    int col = (wn * 4 + nf) * 16 + l15;
    s2[nf] = S[col]; tb2[nf] = Tb[col]; w2v[nf] = W2[col];
  }
  #pragma unroll
  for (int mf = 0; mf < 2; ++mf) {
    const int rbase = wm * 32 + mf * 16 + lg * 4;
    #pragma unroll
    for (int reg = 0; reg < 4; ++reg) {
      const int row = rbase + reg;
      float mu = smu[row], rs = srs[row];
      float part = 0.f;
      #pragma unroll
      for (int nf = 0; nf < 4; ++nf) {
        float val = accA[mf][nf][reg] + accB[mf][nf][reg] * (1.f / 2048.f);
        float hpre = rs * val - rs * mu * s2[nf] + tb2[nf];
        float g = 0.5f * hpre * (1.f + erff(hpre * 0.70710678118654752f));
        part = fmaf(g, w2v[nf], part);
      }
      part += __shfl_xor(part, 1); part += __shfl_xor(part, 2);
      part += __shfl_xor(part, 4); part += __shfl_xor(part, 8);
      if (l15 == 0) sred[row][wn] = part;
    }
  }
  __syncthreads();
  if (tid < 64) {
    float sc = b2[0] + sred[tid][0] + sred[tid][1] + sred[tid][2] + sred[tid][3];
    scores_out[RM + tid] = sc;
  }
}

// ---------------- topk stage 1: 64 blocks, each sorts a 1024-score chunk
// (keys ascending = scores descending, idx-asc ties) and keeps top 512.
__global__ __launch_bounds__(512) void topk_stage1(
    const float* __restrict__ scores, u64* __restrict__ kout) {
  __shared__ u64 keys[1024];
  const int blk = blockIdx.x;
  const int batch = blk >> 3, chunk = blk & 7;
  const int t = threadIdx.x;
  #pragma unroll
  for (int j = 0; j < 2; ++j) {
    int i = t + j * 512;
    int gi = chunk * 1024 + i;                 // within-batch index
    unsigned u = __float_as_uint(scores[(size_t)batch * Lk + gi]);
    unsigned mono = (u & 0x80000000u) ? ~u : (u | 0x80000000u);
    keys[i] = ((u64)(~mono) << 32) | (unsigned)gi;
  }
  __syncthreads();
  for (int size = 2; size <= 1024; size <<= 1) {
    for (int stride = size >> 1; stride > 0; stride >>= 1) {
      int lo = ((t & ~(stride - 1)) << 1) | (t & (stride - 1));
      int hi = lo + stride;
      bool up = ((lo & size) == 0);
      u64 a = keys[lo], c = keys[hi];
      if ((a > c) == up) { keys[lo] = c; keys[hi] = a; }
      __syncthreads();
    }
  }
  kout[(size_t)blk * 512 + t] = keys[t];       // smallest 512 keys = top scores
}

// ---------------- topk stage 2: 8 blocks, tree-merge 8 sorted 512-lists.
// merge(two asc 512): m[i] = min(A[i], B[511-i]) (bitonic) -> 9-stage merge.
__global__ __launch_bounds__(512) void topk_stage2(
    const u64* __restrict__ kin, int k,
    float* __restrict__ idx_f, int* __restrict__ idx_i) {
  __shared__ u64 kk[4096];
  __shared__ u64 tmp[2048];
  const int b = blockIdx.x, t = threadIdx.x;
  #pragma unroll
  for (int j = 0; j < 8; ++j) kk[t + j * 512] = kin[(size_t)b * 4096 + t + j * 512];
  __syncthreads();
  // level 0: kk (8 runs) -> tmp (4 runs)
  #pragma unroll
  for (int j = 0; j < 4; ++j) {
    u64 a = kk[j * 1024 + t];
    u64 c = kk[j * 1024 + 512 + (511 - t)];
    tmp[j * 512 + t] = a < c ? a : c;
  }
  __syncthreads();
  for (int stride = 256; stride > 0; stride >>= 1) {
    #pragma unroll
    for (int w = 0; w < 2; ++w) {
      int p = t + w * 512;                     // 1024 disjoint pairs
      int r = p >> 8, q = p & 255;
      int lo = r * 512 + (((q & ~(stride - 1)) << 1) | (q & (stride - 1)));
      u64 a = tmp[lo], c = tmp[lo + stride];
      if (a > c) { tmp[lo] = c; tmp[lo + stride] = a; }
    }
    __syncthreads();
  }
  // level 1: tmp (4 runs) -> kk (2 runs)
  #pragma unroll
  for (int j = 0; j < 2; ++j) {
    u64 a = tmp[j * 1024 + t];
    u64 c = tmp[j * 1024 + 512 + (511 - t)];
    kk[j * 512 + t] = a < c ? a : c;
  }
  __syncthreads();
  for (int stride = 256; stride > 0; stride >>= 1) {
    int r = t >> 8, q = t & 255;               // 512 pairs over 2 runs
    int lo = r * 512 + (((q & ~(stride - 1)) << 1) | (q & (stride - 1)));
    u64 a = kk[lo], c = kk[lo + stride];
    if (a > c) { kk[lo] = c; kk[lo + stride] = a; }
    __syncthreads();
  }
  // level 2: kk (2 runs) -> tmp[0..512)
  {
    u64 a = kk[t];
    u64 c = kk[512 + (511 - t)];
    tmp[t] = a < c ? a : c;
  }
  __syncthreads();
  for (int stride = 256; stride > 0; stride >>= 1) {
    if (t < 256) {
      int lo = ((t & ~(stride - 1)) << 1) | (t & (stride - 1));
      u64 a = tmp[lo], c = tmp[lo + stride];
      if (a > c) { tmp[lo] = c; tmp[lo + stride] = a; }
    }
    __syncthreads();
  }
  if (t < k) {
    int id = (int)(tmp[t] & 0xFFFFFFFFu);
    idx_f[(size_t)b * k + t] = (float)id;
    idx_i[(size_t)b * k + t] = id;
  }
}

// ---------------- gather: one block per selected row, 4 KB float4 copy
__global__ __launch_bounds__(256) void gather_kernel(
    const float* __restrict__ F, const int* __restrict__ idx,
    float* __restrict__ out, int k) {
  int row = blockIdx.x;          // 0 .. 8*k-1
  int b = row / k;
  int id = idx[row];
  const float4* src = reinterpret_cast<const float4*>(F + ((size_t)b * Lk + id) * Dk);
  float4* dst = reinterpret_cast<float4*>(out + (size_t)row * Dk);
  dst[threadIdx.x] = src[threadIdx.x];
}

extern "C" void kernel_launch(void* const* d_in, const int* in_sizes, int n_in,
                              void* d_out, int out_size, void* d_ws, size_t ws_size,
                              hipStream_t stream) {
  const float* F     = (const float*)d_in[0];
  const float* gamma = (const float*)d_in[1];
  const float* beta  = (const float*)d_in[2];
  const float* W1    = (const float*)d_in[3];
  const float* b1    = (const float*)d_in[4];
  const float* W2    = (const float*)d_in[5];
  const float* b2    = (const float*)d_in[6];
  // k lives on device; derive on host from out_size = 8*k*1024 + 8*8192 + 8*k
  int k = (out_size - Bk * Lk) / (Bk * Dk + Bk);   // = 512

  float* out_sel = (float*)d_out;                       // [8, k, 1024]
  float* out_sc  = out_sel + (size_t)Bk * k * Dk;       // [8, 8192]
  float* out_idx = out_sc + (size_t)Bk * Lk;            // [8, k] as float

  // ws: W1F f16[524288] (1MB) | kout u64[32768] (256KB) | Spart f32[16384] |
  //     Tpart f32[16384] | S f32[256] | Tb f32[256] | idxi i32[8*k]
  f16*   W1F   = (f16*)d_ws;
  u64*   kout  = (u64*)((char*)d_ws + (1 << 20));
  float* Spart = (float*)((char*)kout + 262144);
  float* Tpart = Spart + 16384;
  float* Sp    = Tpart + 16384;
  float* Tbp   = Sp + Hk;
  int*   idxi  = (int*)(Tbp + Hk);

  hipLaunchKernelGGL(prep_split,   dim3(64),        dim3(1024), 0, stream,
                     W1, gamma, beta, W1F, Spart, Tpart);
  hipLaunchKernelGGL(prep_combine, dim3(1),         dim3(Hk),   0, stream,
                     Spart, Tpart, b1, Sp, Tbp);
  hipLaunchKernelGGL(scores_mfma,  dim3(MTOT / 64), dim3(512),  0, stream,
                     F, W1F, Sp, Tbp, W2, b2, out_sc);
  hipLaunchKernelGGL(topk_stage1,  dim3(64),        dim3(512),  0, stream,
                     out_sc, kout);
  hipLaunchKernelGGL(topk_stage2,  dim3(Bk),        dim3(512),  0, stream,
                     kout, k, out_idx, idxi);
  hipLaunchKernelGGL(gather_kernel, dim3(Bk * k),   dim3(256),  0, stream,
                     F, idxi, out_sel, k);
}